// Round 2
// baseline (1275.439 us; speedup 1.0000x reference)
//
#include <hip/hip_runtime.h>
#include <cstddef>
#include <cstdint>

#define T_ 12
#define H_ 64
#define CIN_ 16
#define F_ 768          // H*T
#define PAD_ROW 772
#define BN_EPS 1e-5f

// ---------------- CSR build ----------------

__global__ void k_init(int* __restrict__ cnt, int* __restrict__ cursor, int n) {
    int i = blockIdx.x * 256 + threadIdx.x;
    if (i < n) { cnt[i] = 0; cursor[i] = 0; }
}

__global__ void k_count(const int* __restrict__ dstv, int* __restrict__ cnt, int e) {
    int i = blockIdx.x * 256 + threadIdx.x;
    if (i < e) atomicAdd(&cnt[dstv[i]], 1);
}

__global__ void k_dinv(const int* __restrict__ cnt, float* __restrict__ dinv, int n) {
    int i = blockIdx.x * 256 + threadIdx.x;
    if (i < n) dinv[i] = rsqrtf((float)(cnt[i] + 1));   // +1 self loop
}

__global__ void k_scan(const int* __restrict__ cnt, int* __restrict__ row_start, int n) {
    __shared__ int sd[1024];
    __shared__ int carry_s;
    if (threadIdx.x == 0) { carry_s = 0; row_start[0] = 0; }
    __syncthreads();
    for (int base = 0; base < n; base += 1024) {
        int i = base + (int)threadIdx.x;
        int v = (i < n) ? cnt[i] : 0;
        sd[threadIdx.x] = v;
        __syncthreads();
        for (int off = 1; off < 1024; off <<= 1) {
            int t = (threadIdx.x >= (unsigned)off) ? sd[threadIdx.x - off] : 0;
            __syncthreads();
            sd[threadIdx.x] += t;
            __syncthreads();
        }
        int carry = carry_s;
        if (i < n) row_start[i + 1] = carry + sd[threadIdx.x];
        __syncthreads();
        if (threadIdx.x == 1023) carry_s = carry + sd[1023];
        __syncthreads();
    }
}

__global__ void k_scatter(const int* __restrict__ srcv, const int* __restrict__ dstv,
                          const int* __restrict__ row_start, int* __restrict__ cursor,
                          const float* __restrict__ dinv, int* __restrict__ csr_src,
                          float* __restrict__ csr_coef, int e) {
    int i = blockIdx.x * 256 + threadIdx.x;
    if (i < e) {
        int d = dstv[i], s = srcv[i];
        int pos = atomicAdd(&cursor[d], 1);
        int idx = row_start[d] + pos;
        csr_src[idx]  = s;
        csr_coef[idx] = dinv[s] * dinv[d];
    }
}

// ---------------- embedding: xst[n, t*64+h] = relu(x[n,t,:] @ We + be) ----------------

__global__ __launch_bounds__(256) void k_embed(const float* __restrict__ x,
                                               const float* __restrict__ We,
                                               const float* __restrict__ be,
                                               float* __restrict__ xst, int nT) {
    __shared__ float sW[CIN_ * H_];  // [c*64+h]
    __shared__ float sb[H_];
    for (int i = threadIdx.x; i < CIN_ * H_; i += 256) sW[i] = We[i];
    if (threadIdx.x < H_) sb[threadIdx.x] = be[threadIdx.x];
    __syncthreads();
    int h4  = threadIdx.x & 15;
    int ntl = threadIdx.x >> 4;
    int nt  = blockIdx.x * 16 + ntl;
    if (nt >= nT) return;
    const float4* xp = (const float4*)(x + (size_t)nt * CIN_);
    float4 xv4[4];
    xv4[0] = xp[0]; xv4[1] = xp[1]; xv4[2] = xp[2]; xv4[3] = xp[3];
    const float* xs = (const float*)xv4;
    float acc[4];
#pragma unroll
    for (int j = 0; j < 4; j++) acc[j] = sb[h4 * 4 + j];
#pragma unroll
    for (int c = 0; c < CIN_; c++) {
        float4 w = *(const float4*)&sW[c * H_ + h4 * 4];
        float xc = xs[c];
        acc[0] += xc * w.x; acc[1] += xc * w.y; acc[2] += xc * w.z; acc[3] += xc * w.w;
    }
    float4 o;
    o.x = fmaxf(acc[0], 0.f); o.y = fmaxf(acc[1], 0.f);
    o.z = fmaxf(acc[2], 0.f); o.w = fmaxf(acc[3], 0.f);
    *(float4*)&xst[(size_t)nt * H_ + h4 * 4] = o;
}

// ---------------- fused ST layer ----------------
// Per block: 8 nodes, 128 threads.
// Phase A: gather agg_x = selfcoef*x + sum_e coef*x[src] into LDS (commuted GCN).
// Phase B: y[d,t] = sum_c aggx[c,t] W[c,d] + gcn_b[d]  (regs), write y back to LDS.
// Phase C: temporal conv(k=3,pad=1) over y, + BN + residual(xin) + ReLU -> xout.
// LDS rows are chunk-XOR-swizzled (chunk ^ (s&3)) so the wave's 4 rows hit
// 4 distinct bank quads per b128 read: conflict-free with ZERO pad ->
// 40960 B total -> 4 blocks/CU (8 waves).

__global__ __launch_bounds__(128) void k_layer(
        const float* __restrict__ xin, float* __restrict__ xout,
        const int* __restrict__ row_start, const int* __restrict__ csr_src,
        const float* __restrict__ csr_coef, const float* __restrict__ dinv,
        const float* __restrict__ W, const float* __restrict__ gb,
        const float* __restrict__ cw, const float* __restrict__ cb,
        const float* __restrict__ bng, const float* __restrict__ bnb,
        const float* __restrict__ bnm, const float* __restrict__ bnv,
        int n) {
    __shared__ float sx[8 * F_];     // 24576 B, swizzled chunks
    __shared__ float sw[64 * 64];    // 16384 B, [c*64 + d]
    int tid = threadIdx.x;
    int n0 = blockIdx.x * 8;

    // stage GCN weight [c][d]
    for (int i = tid; i < 4096; i += 128) sw[i] = W[i];

    // ---- Phase A: gather/aggregate ----
    {
        int j4a = tid;          // float4 chunk 0..127
        int j4b = 128 + tid;    // chunk 128..191 (tid<64 only)
        for (int s = 0; s < 8; s++) {
            int nn = n0 + s; if (nn >= n) nn = n - 1;
            float dn = dinv[nn];
            float cs = dn * dn;
            const float4* xp = (const float4*)(xin + (size_t)nn * F_);
            float4 va = xp[j4a];
            float4 acca = make_float4(cs * va.x, cs * va.y, cs * va.z, cs * va.w);
            float4 accb = make_float4(0.f, 0.f, 0.f, 0.f);
            if (tid < 64) {
                float4 vb = xp[j4b];
                accb = make_float4(cs * vb.x, cs * vb.y, cs * vb.z, cs * vb.w);
            }
            int beg = row_start[nn], end = row_start[nn + 1];
            for (int e = beg; e < end; e++) {
                int src = csr_src[e];
                float cf = csr_coef[e];
                const float4* sp = (const float4*)(xin + (size_t)src * F_);
                float4 ua = sp[j4a];
                acca.x += cf * ua.x; acca.y += cf * ua.y;
                acca.z += cf * ua.z; acca.w += cf * ua.w;
                if (tid < 64) {
                    float4 ub = sp[j4b];
                    accb.x += cf * ub.x; accb.y += cf * ub.y;
                    accb.z += cf * ub.z; accb.w += cf * ub.w;
                }
            }
            int s3 = s & 3;
            *(float4*)&sx[s * F_ + 4 * (j4a ^ s3)] = acca;
            if (tid < 64) *(float4*)&sx[s * F_ + 4 * (j4b ^ s3)] = accb;
        }
    }
    __syncthreads();

    int s  = tid >> 4;         // 0..7
    int d4 = tid & 15;         // 0..15, outputs d4*4 .. d4*4+3
    int s3 = s & 3;
    const float* xr = &sx[s * F_];

    // ---- Phase B: GCN linear ----
    float acc[4][12];
    {
        float4 gbv = *(const float4*)&gb[d4 * 4];
        const float gba[4] = {gbv.x, gbv.y, gbv.z, gbv.w};
#pragma unroll
        for (int j = 0; j < 4; j++)
#pragma unroll
            for (int t = 0; t < 12; t++) acc[j][t] = gba[j];
        for (int c = 0; c < 64; c++) {
            float4 q0 = *(const float4*)&xr[4 * ((3 * c + 0) ^ s3)];
            float4 q1 = *(const float4*)&xr[4 * ((3 * c + 1) ^ s3)];
            float4 q2 = *(const float4*)&xr[4 * ((3 * c + 2) ^ s3)];
            float xv[12] = {q0.x, q0.y, q0.z, q0.w, q1.x, q1.y, q1.z, q1.w,
                            q2.x, q2.y, q2.z, q2.w};
            float4 w = *(const float4*)&sw[c * 64 + d4 * 4];
#pragma unroll
            for (int t = 0; t < 12; t++) {
                acc[0][t] += w.x * xv[t]; acc[1][t] += w.y * xv[t];
                acc[2][t] += w.z * xv[t]; acc[3][t] += w.w * xv[t];
            }
        }
    }
    __syncthreads();
    // write y back into sx (same swizzle)
#pragma unroll
    for (int j = 0; j < 4; j++) {
        int d = d4 * 4 + j;
#pragma unroll
        for (int q = 0; q < 3; q++) {
            float4 o;
            o.x = acc[j][q * 4 + 0]; o.y = acc[j][q * 4 + 1];
            o.z = acc[j][q * 4 + 2]; o.w = acc[j][q * 4 + 3];
            *(float4*)&sx[s * F_ + 4 * ((3 * d + q) ^ s3)] = o;
        }
    }
    __syncthreads();

    // ---- Phase C: temporal conv + BN + residual + ReLU ----
    float acc2[4][12];
#pragma unroll
    for (int j = 0; j < 4; j++)
#pragma unroll
        for (int t = 0; t < 12; t++) acc2[j][t] = 0.f;
#pragma unroll
    for (int k = 0; k < 3; k++) {
        // stage conv plane k: sw[c*64+o] = cw[o][c][k]
        for (int i = tid; i < 4096; i += 128) {
            int o = i >> 6, c = i & 63;
            sw[c * 64 + o] = cw[(size_t)(o * 64 + c) * 3 + k];
        }
        __syncthreads();
        for (int c = 0; c < 64; c++) {
            float4 q0 = *(const float4*)&xr[4 * ((3 * c + 0) ^ s3)];
            float4 q1 = *(const float4*)&xr[4 * ((3 * c + 1) ^ s3)];
            float4 q2 = *(const float4*)&xr[4 * ((3 * c + 2) ^ s3)];
            float xv[12] = {q0.x, q0.y, q0.z, q0.w, q1.x, q1.y, q1.z, q1.w,
                            q2.x, q2.y, q2.z, q2.w};
            float4 w = *(const float4*)&sw[c * 64 + d4 * 4];
#pragma unroll
            for (int t = 0; t < 12; t++) {
                int tt = t + k - 1;
                if (tt >= 0 && tt < 12) {
                    float xc = xv[tt];
                    acc2[0][t] += w.x * xc; acc2[1][t] += w.y * xc;
                    acc2[2][t] += w.z * xc; acc2[3][t] += w.w * xc;
                }
            }
        }
        __syncthreads();
    }

    int nn = n0 + s;
    if (nn < n) {
        const float* rp = xin + (size_t)nn * F_;
        float* op = xout + (size_t)nn * F_;
#pragma unroll
        for (int j = 0; j < 4; j++) {
            int o = d4 * 4 + j;
            float scale = bng[o] * rsqrtf(bnv[o] + BN_EPS);
            float shift = bnb[o] - bnm[o] * scale + cb[o] * scale;
#pragma unroll
            for (int q = 0; q < 3; q++) {
                float4 r = *(const float4*)&rp[o * 12 + q * 4];
                float4 w;
                w.x = fmaxf(acc2[j][q * 4 + 0] * scale + shift + r.x, 0.f);
                w.y = fmaxf(acc2[j][q * 4 + 1] * scale + shift + r.y, 0.f);
                w.z = fmaxf(acc2[j][q * 4 + 2] * scale + shift + r.z, 0.f);
                w.w = fmaxf(acc2[j][q * 4 + 3] * scale + shift + r.w, 0.f);
                *(float4*)&op[o * 12 + q * 4] = w;
            }
        }
    }
}

// ---------------- dual attention + output MLP ----------------

__global__ __launch_bounds__(128) void k_attn(const float* __restrict__ xst,
        const float* __restrict__ taw1, const float* __restrict__ tab1,
        const float* __restrict__ taw2, const float* __restrict__ tab2,
        const float* __restrict__ faw1, const float* __restrict__ fab1,
        const float* __restrict__ faw2, const float* __restrict__ fab2,
        const float* __restrict__ ow1, const float* __restrict__ ob1,
        const float* __restrict__ ow2, const float* __restrict__ ob2,
        float* __restrict__ out, int n) {
    __shared__ float sT[8 * PAD_ROW];       // [s][h*12+t]
    __shared__ float s_taw1[2048];          // [h*32+m]
    __shared__ float s_ow1[2048];           // [h*32+m]
    __shared__ float s_tab1[32], s_taw2[32], s_ob1[32], s_ow2[32];
    __shared__ float s_faw1[72], s_fab1[8], s_faw2[8];
    __shared__ float s_tw[8 * 12];
    __shared__ float s_xf[8 * 65];
    int tid = threadIdx.x;
    int n0 = blockIdx.x * 8;
    for (int i = tid; i < 2048; i += 128) { s_taw1[i] = taw1[i]; s_ow1[i] = ow1[i]; }
    if (tid < 32) {
        s_tab1[tid] = tab1[tid]; s_taw2[tid] = taw2[tid];
        s_ob1[tid] = ob1[tid];   s_ow2[tid] = ow2[tid];
    }
    if (tid < 72) s_faw1[tid] = faw1[tid];
    if (tid < 6) { s_fab1[tid] = fab1[tid]; s_faw2[tid] = faw2[tid]; }
    float tb2 = tab2[0], fb2 = fab2[0], o_b2 = ob2[0];
    for (int i = tid; i < 8 * F_; i += 128) {
        int s = i / F_, j = i - s * F_;
        int t = j >> 6, hh = j & 63;
        int nn = n0 + s; if (nn >= n) nn = n - 1;
        sT[s * PAD_ROW + hh * 12 + t] = xst[(size_t)nn * F_ + j];
    }
    __syncthreads();

    int s = tid >> 4, m2 = tid & 15;
    {
        float a0[12], a1[12];
        float b0 = s_tab1[2 * m2], b1 = s_tab1[2 * m2 + 1];
#pragma unroll
        for (int t = 0; t < 12; t++) { a0[t] = b0; a1[t] = b1; }
        const float* xr = &sT[s * PAD_ROW];
        for (int hh = 0; hh < 64; hh++) {
            float4 q0 = *(const float4*)&xr[hh * 12];
            float4 q1 = *(const float4*)&xr[hh * 12 + 4];
            float4 q2 = *(const float4*)&xr[hh * 12 + 8];
            float xv[12] = {q0.x, q0.y, q0.z, q0.w, q1.x, q1.y, q1.z, q1.w, q2.x, q2.y, q2.z, q2.w};
            float w0 = s_taw1[hh * 32 + 2 * m2], w1 = s_taw1[hh * 32 + 2 * m2 + 1];
#pragma unroll
            for (int t = 0; t < 12; t++) { a0[t] += w0 * xv[t]; a1[t] += w1 * xv[t]; }
        }
        float w20 = s_taw2[2 * m2], w21 = s_taw2[2 * m2 + 1];
#pragma unroll
        for (int t = 0; t < 12; t++) {
            float p = fmaxf(a0[t], 0.f) * w20 + fmaxf(a1[t], 0.f) * w21;
            p += __shfl_xor(p, 1); p += __shfl_xor(p, 2);
            p += __shfl_xor(p, 4); p += __shfl_xor(p, 8);
            if (m2 == 0) s_tw[s * 12 + t] = p + tb2;
        }
    }
    __syncthreads();

    int wave = tid >> 6, lane = tid & 63;
    for (int q = 0; q < 4; q++) {
        int ss = wave * 4 + q;
        float tw[12];
#pragma unroll
        for (int t = 0; t < 12; t++) tw[t] = s_tw[ss * 12 + t];
        float mx = tw[0];
#pragma unroll
        for (int t = 1; t < 12; t++) mx = fmaxf(mx, tw[t]);
        float sum = 0.f;
#pragma unroll
        for (int t = 0; t < 12; t++) { tw[t] = __expf(tw[t] - mx); sum += tw[t]; }
        float inv = 1.f / sum;
        const float* xr = &sT[ss * PAD_ROW + lane * 12];
        float4 q0 = *(const float4*)(xr);
        float4 q1 = *(const float4*)(xr + 4);
        float4 q2 = *(const float4*)(xr + 8);
        float xv[12] = {q0.x, q0.y, q0.z, q0.w, q1.x, q1.y, q1.z, q1.w, q2.x, q2.y, q2.z, q2.w};
        float xt[12];
#pragma unroll
        for (int t = 0; t < 12; t++) xt[t] = xv[t] * tw[t] * inv;
        float lf = fb2;
#pragma unroll
        for (int mm = 0; mm < 6; mm++) {
            float v = s_fab1[mm];
#pragma unroll
            for (int t = 0; t < 12; t++) v += xt[t] * s_faw1[t * 6 + mm];
            lf += fmaxf(v, 0.f) * s_faw2[mm];
        }
        float m2v = lf;
#pragma unroll
        for (int off = 32; off >= 1; off >>= 1) m2v = fmaxf(m2v, __shfl_xor(m2v, off));
        float e = __expf(lf - m2v);
        float se = e;
#pragma unroll
        for (int off = 32; off >= 1; off >>= 1) se += __shfl_xor(se, off);
        float fwv = e / se;
        float xs = 0.f;
#pragma unroll
        for (int t = 0; t < 12; t++) xs += xt[t];
        s_xf[ss * 65 + lane] = fwv * xs;
    }
    __syncthreads();

    {
        float v0 = s_ob1[2 * m2], v1 = s_ob1[2 * m2 + 1];
        const float* xfp = &s_xf[s * 65];
        for (int hh = 0; hh < 64; hh++) {
            float xv = xfp[hh];
            v0 += xv * s_ow1[hh * 32 + 2 * m2];
            v1 += xv * s_ow1[hh * 32 + 2 * m2 + 1];
        }
        float p = fmaxf(v0, 0.f) * s_ow2[2 * m2] + fmaxf(v1, 0.f) * s_ow2[2 * m2 + 1];
        p += __shfl_xor(p, 1); p += __shfl_xor(p, 2);
        p += __shfl_xor(p, 4); p += __shfl_xor(p, 8);
        if (m2 == 0 && n0 + s < n) out[n0 + s] = p + o_b2;
    }
}

// ---------------- launcher ----------------

extern "C" void kernel_launch(void* const* d_in, const int* in_sizes, int n_in,
                              void* d_out, int out_size, void* d_ws, size_t ws_size,
                              hipStream_t stream) {
    const float* x      = (const float*)d_in[0];
    const int*   ei     = (const int*)d_in[1];
    const float* We     = (const float*)d_in[2];
    const float* be     = (const float*)d_in[3];
    const float* gcn_W  = (const float*)d_in[4];
    const float* gcn_b  = (const float*)d_in[5];
    const float* conv_w = (const float*)d_in[6];
    const float* conv_b = (const float*)d_in[7];
    const float* bn_g   = (const float*)d_in[8];
    const float* bn_b   = (const float*)d_in[9];
    const float* bn_m   = (const float*)d_in[10];
    const float* bn_v   = (const float*)d_in[11];
    const float* ta_w1  = (const float*)d_in[12];
    const float* ta_b1  = (const float*)d_in[13];
    const float* ta_w2  = (const float*)d_in[14];
    const float* ta_b2  = (const float*)d_in[15];
    const float* fa_w1  = (const float*)d_in[16];
    const float* fa_b1  = (const float*)d_in[17];
    const float* fa_w2  = (const float*)d_in[18];
    const float* fa_b2  = (const float*)d_in[19];
    const float* ow1    = (const float*)d_in[20];
    const float* ob1    = (const float*)d_in[21];
    const float* ow2    = (const float*)d_in[22];
    const float* ob2    = (const float*)d_in[23];

    int n = in_sizes[0] / (T_ * CIN_);
    int e = in_sizes[1] / 2;
    const int* srcv = ei;
    const int* dstv = ei + e;

    char* p = (char*)d_ws;
    auto take = [&](size_t bytes) -> void* {
        void* r = (void*)p;
        p += (bytes + 255) & ~(size_t)255;
        return r;
    };
    int*   cnt       = (int*)take((size_t)n * 4);
    int*   cursor    = (int*)take((size_t)n * 4);
    int*   row_start = (int*)take(((size_t)n + 1) * 4);
    float* dinv      = (float*)take((size_t)n * 4);
    int*   csr_src   = (int*)take((size_t)e * 4);
    float* csr_coef  = (float*)take((size_t)e * 4);
    float* xa        = (float*)take((size_t)n * F_ * 4);
    float* xb        = (float*)take((size_t)n * F_ * 4);

    int nb_n = (n + 255) / 256;
    int nb_e = (e + 255) / 256;

    k_init<<<nb_n, 256, 0, stream>>>(cnt, cursor, n);
    k_count<<<nb_e, 256, 0, stream>>>(dstv, cnt, e);
    k_dinv<<<nb_n, 256, 0, stream>>>(cnt, dinv, n);
    k_scan<<<1, 1024, 0, stream>>>(cnt, row_start, n);
    k_scatter<<<nb_e, 256, 0, stream>>>(srcv, dstv, row_start, cursor, dinv,
                                        csr_src, csr_coef, e);

    int nT = n * T_;
    k_embed<<<(nT + 15) / 16, 256, 0, stream>>>(x, We, be, xa, nT);

    int nb8 = (n + 7) / 8;
    const float* cur = xa;
    float* nxt = xb;
    for (int i = 0; i < 3; i++) {
        k_layer<<<nb8, 128, 0, stream>>>(cur, nxt, row_start, csr_src, csr_coef,
                                         dinv,
                                         gcn_W + (size_t)i * H_ * H_,
                                         gcn_b + (size_t)i * H_,
                                         conv_w + (size_t)i * H_ * H_ * 3,
                                         conv_b + (size_t)i * H_,
                                         bn_g + (size_t)i * H_, bn_b + (size_t)i * H_,
                                         bn_m + (size_t)i * H_, bn_v + (size_t)i * H_,
                                         n);
        const float* tmp = nxt;
        nxt = (float*)cur == xa ? xb : ((float*)cur == xb ? xa : xb);
        nxt = (float*)((cur == xa) ? (void*)xb : (void*)xa);
        cur = tmp;
        nxt = (cur == xa) ? xb : xa;
    }

    k_attn<<<nb8, 128, 0, stream>>>(cur, ta_w1, ta_b1, ta_w2, ta_b2,
                                    fa_w1, fa_b1, fa_w2, fa_b2,
                                    ow1, ob1, ow2, ob2, (float*)d_out, n);
}

// Round 3
// 1020.060 us; speedup vs baseline: 1.2504x; 1.2504x over previous
//
#include <hip/hip_runtime.h>
#include <cstddef>
#include <cstdint>

#define T_ 12
#define H_ 64
#define CIN_ 16
#define F_ 768          // H*T
#define PAD_ROW 772
#define BN_EPS 1e-5f

// ---------------- CSR build ----------------

__global__ void k_init(int* __restrict__ cnt, int* __restrict__ cursor, int n) {
    int i = blockIdx.x * 256 + threadIdx.x;
    if (i < n) { cnt[i] = 0; cursor[i] = 0; }
}

__global__ void k_count(const int* __restrict__ dstv, int* __restrict__ cnt, int e) {
    int i = blockIdx.x * 256 + threadIdx.x;
    if (i < e) atomicAdd(&cnt[dstv[i]], 1);
}

__global__ void k_dinv(const int* __restrict__ cnt, float* __restrict__ dinv, int n) {
    int i = blockIdx.x * 256 + threadIdx.x;
    if (i < n) dinv[i] = rsqrtf((float)(cnt[i] + 1));   // +1 self loop
}

__global__ void k_scan(const int* __restrict__ cnt, int* __restrict__ row_start, int n) {
    __shared__ int sd[1024];
    __shared__ int carry_s;
    if (threadIdx.x == 0) { carry_s = 0; row_start[0] = 0; }
    __syncthreads();
    for (int base = 0; base < n; base += 1024) {
        int i = base + (int)threadIdx.x;
        int v = (i < n) ? cnt[i] : 0;
        sd[threadIdx.x] = v;
        __syncthreads();
        for (int off = 1; off < 1024; off <<= 1) {
            int t = (threadIdx.x >= (unsigned)off) ? sd[threadIdx.x - off] : 0;
            __syncthreads();
            sd[threadIdx.x] += t;
            __syncthreads();
        }
        int carry = carry_s;
        if (i < n) row_start[i + 1] = carry + sd[threadIdx.x];
        __syncthreads();
        if (threadIdx.x == 1023) carry_s = carry + sd[1023];
        __syncthreads();
    }
}

__global__ void k_scatter(const int* __restrict__ srcv, const int* __restrict__ dstv,
                          const int* __restrict__ row_start, int* __restrict__ cursor,
                          const float* __restrict__ dinv, int* __restrict__ csr_src,
                          float* __restrict__ csr_coef, int e) {
    int i = blockIdx.x * 256 + threadIdx.x;
    if (i < e) {
        int d = dstv[i], s = srcv[i];
        int pos = atomicAdd(&cursor[d], 1);
        int idx = row_start[d] + pos;
        csr_src[idx]  = s;
        csr_coef[idx] = dinv[s] * dinv[d];
    }
}

// ---------------- weight prep: fold GCN W into conv planes ----------------
// Wk[l][k][c][o] = sum_d gcn_W[l][c][d] * conv_w[l][o][d][k]
// bk[l][k][o]    = sum_d gcn_b[l][d]    * conv_w[l][o][d][k]
// 36 blocks: l = b/12, k = (b/4)%3, cq = b%4 (16 c-rows each), 256 thr.

__global__ __launch_bounds__(256) void k_wprep(const float* __restrict__ gcn_W,
                                               const float* __restrict__ gcn_b,
                                               const float* __restrict__ conv_w,
                                               float* __restrict__ wkp,
                                               float* __restrict__ bkp) {
    int b = blockIdx.x;
    int l = b / 12, k = (b / 4) % 3, cq = b & 3;
    const float* Wg = gcn_W + (size_t)l * 4096;
    const float* cw = conv_w + (size_t)l * 12288;
    int tid = threadIdx.x;
#pragma unroll
    for (int j = 0; j < 4; j++) {
        int idx = j * 256 + tid;            // 0..1023
        int c = cq * 16 + (idx >> 6);
        int o = idx & 63;
        float acc = 0.f;
        for (int d = 0; d < 64; d++)
            acc += Wg[c * 64 + d] * cw[(size_t)(o * 64 + d) * 3 + k];
        wkp[(((size_t)l * 3 + k) * 64 + c) * 64 + o] = acc;
    }
    if (cq == 0 && tid < 64) {
        int o = tid;
        const float* gb = gcn_b + (size_t)l * 64;
        float acc = 0.f;
        for (int d = 0; d < 64; d++)
            acc += gb[d] * cw[(size_t)(o * 64 + d) * 3 + k];
        bkp[((size_t)l * 3 + k) * 64 + o] = acc;
    }
}

// ---------------- embedding: xst[n, t*64+h] = relu(x[n,t,:] @ We + be) ----------------

__global__ __launch_bounds__(256) void k_embed(const float* __restrict__ x,
                                               const float* __restrict__ We,
                                               const float* __restrict__ be,
                                               float* __restrict__ xst, int nT) {
    __shared__ float sW[CIN_ * H_];  // [c*64+h]
    __shared__ float sb[H_];
    for (int i = threadIdx.x; i < CIN_ * H_; i += 256) sW[i] = We[i];
    if (threadIdx.x < H_) sb[threadIdx.x] = be[threadIdx.x];
    __syncthreads();
    int h4  = threadIdx.x & 15;
    int ntl = threadIdx.x >> 4;
    int nt  = blockIdx.x * 16 + ntl;
    if (nt >= nT) return;
    const float4* xp = (const float4*)(x + (size_t)nt * CIN_);
    float4 xv4[4];
    xv4[0] = xp[0]; xv4[1] = xp[1]; xv4[2] = xp[2]; xv4[3] = xp[3];
    const float* xs = (const float*)xv4;
    float acc[4];
#pragma unroll
    for (int j = 0; j < 4; j++) acc[j] = sb[h4 * 4 + j];
#pragma unroll
    for (int c = 0; c < CIN_; c++) {
        float4 w = *(const float4*)&sW[c * H_ + h4 * 4];
        float xc = xs[c];
        acc[0] += xc * w.x; acc[1] += xc * w.y; acc[2] += xc * w.z; acc[3] += xc * w.w;
    }
    float4 o;
    o.x = fmaxf(acc[0], 0.f); o.y = fmaxf(acc[1], 0.f);
    o.z = fmaxf(acc[2], 0.f); o.w = fmaxf(acc[3], 0.f);
    *(float4*)&xst[(size_t)nt * H_ + h4 * 4] = o;
}

// ---------------- fused ST layer (GCN linear folded into conv weights) ----------
// Per block: 8 nodes, 128 threads (2 waves).
// Phase A: wave w gathers nodes s = 4w..4w+3; each lane owns chunks
//          {lane, lane+64, lane+128}: full 768-float row per wave per edge,
//          edge loop unrolled x2 -> 6 independent dwordx4 loads in flight.
// Phase C: conv over the aggregated x with the 3 folded planes, + bias edge
//          corrections + BN + residual + ReLU.
// XOR chunk swizzle (chunk ^ (s&3)) keeps LDS conflict-free with zero pad:
// 24576 + 16384 = 40960 B -> 4 blocks/CU (8 waves).

#define FMA4(acc, cf, u) \
    acc.x += cf * u.x; acc.y += cf * u.y; acc.z += cf * u.z; acc.w += cf * u.w;

__global__ __launch_bounds__(128) void k_layer(
        const float* __restrict__ xin, float* __restrict__ xout,
        const int* __restrict__ row_start, const int* __restrict__ csr_src,
        const float* __restrict__ csr_coef, const float* __restrict__ dinv,
        const float* __restrict__ wkp,    // [3][64][64] folded planes (this layer)
        const float* __restrict__ bkp,    // [3][64]
        const float* __restrict__ cb,
        const float* __restrict__ bng, const float* __restrict__ bnb,
        const float* __restrict__ bnm, const float* __restrict__ bnv,
        int n) {
    __shared__ float sx[8 * F_];     // 24576 B, swizzled chunks
    __shared__ float sw[64 * 64];    // 16384 B, one folded plane [c*64+o]
    int tid = threadIdx.x;
    int n0 = blockIdx.x * 8;
    int wave = tid >> 6, lane = tid & 63;

    // ---- Phase A: gather/aggregate (per-wave node split) ----
    {
        int c0 = lane, c1 = lane + 64, c2 = lane + 128;
        for (int si = 0; si < 4; si++) {
            int s = wave * 4 + si;
            int nn = n0 + s; if (nn >= n) nn = n - 1;
            float dn = dinv[nn];
            float cs = dn * dn;
            const float4* xp = (const float4*)(xin + (size_t)nn * F_);
            float4 a0 = xp[c0], a1 = xp[c1], a2 = xp[c2];
            a0.x *= cs; a0.y *= cs; a0.z *= cs; a0.w *= cs;
            a1.x *= cs; a1.y *= cs; a1.z *= cs; a1.w *= cs;
            a2.x *= cs; a2.y *= cs; a2.z *= cs; a2.w *= cs;
            int e = row_start[nn], end = row_start[nn + 1];
            for (; e + 1 < end; e += 2) {
                int sA = csr_src[e],  sB = csr_src[e + 1];
                float cA = csr_coef[e], cB = csr_coef[e + 1];
                const float4* pA = (const float4*)(xin + (size_t)sA * F_);
                const float4* pB = (const float4*)(xin + (size_t)sB * F_);
                float4 uA0 = pA[c0], uA1 = pA[c1], uA2 = pA[c2];
                float4 uB0 = pB[c0], uB1 = pB[c1], uB2 = pB[c2];
                FMA4(a0, cA, uA0) FMA4(a1, cA, uA1) FMA4(a2, cA, uA2)
                FMA4(a0, cB, uB0) FMA4(a1, cB, uB1) FMA4(a2, cB, uB2)
            }
            if (e < end) {
                int sA = csr_src[e];
                float cA = csr_coef[e];
                const float4* pA = (const float4*)(xin + (size_t)sA * F_);
                float4 uA0 = pA[c0], uA1 = pA[c1], uA2 = pA[c2];
                FMA4(a0, cA, uA0) FMA4(a1, cA, uA1) FMA4(a2, cA, uA2)
            }
            int s3 = s & 3;
            *(float4*)&sx[s * F_ + 4 * (c0 ^ s3)] = a0;
            *(float4*)&sx[s * F_ + 4 * (c1 ^ s3)] = a1;
            *(float4*)&sx[s * F_ + 4 * (c2 ^ s3)] = a2;
        }
    }
    __syncthreads();

    int s  = tid >> 4;         // 0..7
    int d4 = tid & 15;         // outputs o = d4*4 .. d4*4+3
    int s3 = s & 3;
    const float* xr = &sx[s * F_];

    // ---- Phase C: conv with folded planes ----
    float acc2[4][12];
#pragma unroll
    for (int j = 0; j < 4; j++)
#pragma unroll
        for (int t = 0; t < 12; t++) acc2[j][t] = 0.f;
#pragma unroll
    for (int k = 0; k < 3; k++) {
        {   // stage plane k (contiguous b128, coalesced)
            const float4* wsrc = (const float4*)(wkp + (size_t)k * 4096);
            float4* wdst = (float4*)sw;
            for (int i = tid; i < 1024; i += 128) wdst[i] = wsrc[i];
        }
        __syncthreads();
        for (int c = 0; c < 64; c++) {
            float4 q0 = *(const float4*)&xr[4 * ((3 * c + 0) ^ s3)];
            float4 q1 = *(const float4*)&xr[4 * ((3 * c + 1) ^ s3)];
            float4 q2 = *(const float4*)&xr[4 * ((3 * c + 2) ^ s3)];
            float xv[12] = {q0.x, q0.y, q0.z, q0.w, q1.x, q1.y, q1.z, q1.w,
                            q2.x, q2.y, q2.z, q2.w};
            float4 w = *(const float4*)&sw[c * 64 + d4 * 4];
#pragma unroll
            for (int t = 0; t < 12; t++) {
                int tt = t + k - 1;
                if (tt >= 0 && tt < 12) {
                    float xc = xv[tt];
                    acc2[0][t] += w.x * xc; acc2[1][t] += w.y * xc;
                    acc2[2][t] += w.z * xc; acc2[3][t] += w.w * xc;
                }
            }
        }
        __syncthreads();
    }

    int nn = n0 + s;
    if (nn < n) {
        const float* rp = xin + (size_t)nn * F_;
        float* op = xout + (size_t)nn * F_;
#pragma unroll
        for (int j = 0; j < 4; j++) {
            int o = d4 * 4 + j;
            float scale = bng[o] * rsqrtf(bnv[o] + BN_EPS);
            float shift = bnb[o] - bnm[o] * scale;
            float bk0 = bkp[o], bk1 = bkp[64 + o], bk2 = bkp[128 + o];
            float b_all = cb[o] + bk0 + bk1 + bk2;
#pragma unroll
            for (int q = 0; q < 3; q++) {
                float4 r = *(const float4*)&rp[o * 12 + q * 4];
                float bias0 = b_all - ((q == 0) ? bk0 : 0.f);
                float bias3 = b_all - ((q == 2) ? bk2 : 0.f);
                float4 w;
                w.x = fmaxf((acc2[j][q * 4 + 0] + bias0) * scale + shift + r.x, 0.f);
                w.y = fmaxf((acc2[j][q * 4 + 1] + b_all) * scale + shift + r.y, 0.f);
                w.z = fmaxf((acc2[j][q * 4 + 2] + b_all) * scale + shift + r.z, 0.f);
                w.w = fmaxf((acc2[j][q * 4 + 3] + bias3) * scale + shift + r.w, 0.f);
                *(float4*)&op[o * 12 + q * 4] = w;
            }
        }
    }
}

// ---------------- dual attention + output MLP ----------------

__global__ __launch_bounds__(128) void k_attn(const float* __restrict__ xst,
        const float* __restrict__ taw1, const float* __restrict__ tab1,
        const float* __restrict__ taw2, const float* __restrict__ tab2,
        const float* __restrict__ faw1, const float* __restrict__ fab1,
        const float* __restrict__ faw2, const float* __restrict__ fab2,
        const float* __restrict__ ow1, const float* __restrict__ ob1,
        const float* __restrict__ ow2, const float* __restrict__ ob2,
        float* __restrict__ out, int n) {
    __shared__ float sT[8 * PAD_ROW];       // [s][h*12+t]
    __shared__ float s_taw1[2048];          // [h*32+m]
    __shared__ float s_ow1[2048];           // [h*32+m]
    __shared__ float s_tab1[32], s_taw2[32], s_ob1[32], s_ow2[32];
    __shared__ float s_faw1[72], s_fab1[8], s_faw2[8];
    __shared__ float s_tw[8 * 12];
    __shared__ float s_xf[8 * 65];
    int tid = threadIdx.x;
    int n0 = blockIdx.x * 8;
    for (int i = tid; i < 2048; i += 128) { s_taw1[i] = taw1[i]; s_ow1[i] = ow1[i]; }
    if (tid < 32) {
        s_tab1[tid] = tab1[tid]; s_taw2[tid] = taw2[tid];
        s_ob1[tid] = ob1[tid];   s_ow2[tid] = ow2[tid];
    }
    if (tid < 72) s_faw1[tid] = faw1[tid];
    if (tid < 6) { s_fab1[tid] = fab1[tid]; s_faw2[tid] = faw2[tid]; }
    float tb2 = tab2[0], fb2 = fab2[0], o_b2 = ob2[0];
    for (int i = tid; i < 8 * F_; i += 128) {
        int s = i / F_, j = i - s * F_;
        int t = j >> 6, hh = j & 63;
        int nn = n0 + s; if (nn >= n) nn = n - 1;
        sT[s * PAD_ROW + hh * 12 + t] = xst[(size_t)nn * F_ + j];
    }
    __syncthreads();

    int s = tid >> 4, m2 = tid & 15;
    {
        float a0[12], a1[12];
        float b0 = s_tab1[2 * m2], b1 = s_tab1[2 * m2 + 1];
#pragma unroll
        for (int t = 0; t < 12; t++) { a0[t] = b0; a1[t] = b1; }
        const float* xr = &sT[s * PAD_ROW];
        for (int hh = 0; hh < 64; hh++) {
            float4 q0 = *(const float4*)&xr[hh * 12];
            float4 q1 = *(const float4*)&xr[hh * 12 + 4];
            float4 q2 = *(const float4*)&xr[hh * 12 + 8];
            float xv[12] = {q0.x, q0.y, q0.z, q0.w, q1.x, q1.y, q1.z, q1.w, q2.x, q2.y, q2.z, q2.w};
            float w0 = s_taw1[hh * 32 + 2 * m2], w1 = s_taw1[hh * 32 + 2 * m2 + 1];
#pragma unroll
            for (int t = 0; t < 12; t++) { a0[t] += w0 * xv[t]; a1[t] += w1 * xv[t]; }
        }
        float w20 = s_taw2[2 * m2], w21 = s_taw2[2 * m2 + 1];
#pragma unroll
        for (int t = 0; t < 12; t++) {
            float p = fmaxf(a0[t], 0.f) * w20 + fmaxf(a1[t], 0.f) * w21;
            p += __shfl_xor(p, 1); p += __shfl_xor(p, 2);
            p += __shfl_xor(p, 4); p += __shfl_xor(p, 8);
            if (m2 == 0) s_tw[s * 12 + t] = p + tb2;
        }
    }
    __syncthreads();

    int wave = tid >> 6, lane = tid & 63;
    for (int q = 0; q < 4; q++) {
        int ss = wave * 4 + q;
        float tw[12];
#pragma unroll
        for (int t = 0; t < 12; t++) tw[t] = s_tw[ss * 12 + t];
        float mx = tw[0];
#pragma unroll
        for (int t = 1; t < 12; t++) mx = fmaxf(mx, tw[t]);
        float sum = 0.f;
#pragma unroll
        for (int t = 0; t < 12; t++) { tw[t] = __expf(tw[t] - mx); sum += tw[t]; }
        float inv = 1.f / sum;
        const float* xr = &sT[ss * PAD_ROW + lane * 12];
        float4 q0 = *(const float4*)(xr);
        float4 q1 = *(const float4*)(xr + 4);
        float4 q2 = *(const float4*)(xr + 8);
        float xv[12] = {q0.x, q0.y, q0.z, q0.w, q1.x, q1.y, q1.z, q1.w, q2.x, q2.y, q2.z, q2.w};
        float xt[12];
#pragma unroll
        for (int t = 0; t < 12; t++) xt[t] = xv[t] * tw[t] * inv;
        float lf = fb2;
#pragma unroll
        for (int mm = 0; mm < 6; mm++) {
            float v = s_fab1[mm];
#pragma unroll
            for (int t = 0; t < 12; t++) v += xt[t] * s_faw1[t * 6 + mm];
            lf += fmaxf(v, 0.f) * s_faw2[mm];
        }
        float m2v = lf;
#pragma unroll
        for (int off = 32; off >= 1; off >>= 1) m2v = fmaxf(m2v, __shfl_xor(m2v, off));
        float e = __expf(lf - m2v);
        float se = e;
#pragma unroll
        for (int off = 32; off >= 1; off >>= 1) se += __shfl_xor(se, off);
        float fwv = e / se;
        float xs = 0.f;
#pragma unroll
        for (int t = 0; t < 12; t++) xs += xt[t];
        s_xf[ss * 65 + lane] = fwv * xs;
    }
    __syncthreads();

    {
        float v0 = s_ob1[2 * m2], v1 = s_ob1[2 * m2 + 1];
        const float* xfp = &s_xf[s * 65];
        for (int hh = 0; hh < 64; hh++) {
            float xv = xfp[hh];
            v0 += xv * s_ow1[hh * 32 + 2 * m2];
            v1 += xv * s_ow1[hh * 32 + 2 * m2 + 1];
        }
        float p = fmaxf(v0, 0.f) * s_ow2[2 * m2] + fmaxf(v1, 0.f) * s_ow2[2 * m2 + 1];
        p += __shfl_xor(p, 1); p += __shfl_xor(p, 2);
        p += __shfl_xor(p, 4); p += __shfl_xor(p, 8);
        if (m2 == 0 && n0 + s < n) out[n0 + s] = p + o_b2;
    }
}

// ---------------- launcher ----------------

extern "C" void kernel_launch(void* const* d_in, const int* in_sizes, int n_in,
                              void* d_out, int out_size, void* d_ws, size_t ws_size,
                              hipStream_t stream) {
    const float* x      = (const float*)d_in[0];
    const int*   ei     = (const int*)d_in[1];
    const float* We     = (const float*)d_in[2];
    const float* be     = (const float*)d_in[3];
    const float* gcn_W  = (const float*)d_in[4];
    const float* gcn_b  = (const float*)d_in[5];
    const float* conv_w = (const float*)d_in[6];
    const float* conv_b = (const float*)d_in[7];
    const float* bn_g   = (const float*)d_in[8];
    const float* bn_b   = (const float*)d_in[9];
    const float* bn_m   = (const float*)d_in[10];
    const float* bn_v   = (const float*)d_in[11];
    const float* ta_w1  = (const float*)d_in[12];
    const float* ta_b1  = (const float*)d_in[13];
    const float* ta_w2  = (const float*)d_in[14];
    const float* ta_b2  = (const float*)d_in[15];
    const float* fa_w1  = (const float*)d_in[16];
    const float* fa_b1  = (const float*)d_in[17];
    const float* fa_w2  = (const float*)d_in[18];
    const float* fa_b2  = (const float*)d_in[19];
    const float* ow1    = (const float*)d_in[20];
    const float* ob1    = (const float*)d_in[21];
    const float* ow2    = (const float*)d_in[22];
    const float* ob2    = (const float*)d_in[23];

    int n = in_sizes[0] / (T_ * CIN_);
    int e = in_sizes[1] / 2;
    const int* srcv = ei;
    const int* dstv = ei + e;

    char* p = (char*)d_ws;
    auto take = [&](size_t bytes) -> void* {
        void* r = (void*)p;
        p += (bytes + 255) & ~(size_t)255;
        return r;
    };
    int*   cnt       = (int*)take((size_t)n * 4);
    int*   cursor    = (int*)take((size_t)n * 4);
    int*   row_start = (int*)take(((size_t)n + 1) * 4);
    float* dinv      = (float*)take((size_t)n * 4);
    int*   csr_src   = (int*)take((size_t)e * 4);
    float* csr_coef  = (float*)take((size_t)e * 4);
    float* wkp       = (float*)take((size_t)3 * 3 * 64 * 64 * 4);
    float* bkp       = (float*)take((size_t)3 * 3 * 64 * 4);
    float* xa        = (float*)take((size_t)n * F_ * 4);
    float* xb        = (float*)take((size_t)n * F_ * 4);

    int nb_n = (n + 255) / 256;
    int nb_e = (e + 255) / 256;

    k_wprep<<<36, 256, 0, stream>>>(gcn_W, gcn_b, conv_w, wkp, bkp);
    k_init<<<nb_n, 256, 0, stream>>>(cnt, cursor, n);
    k_count<<<nb_e, 256, 0, stream>>>(dstv, cnt, e);
    k_dinv<<<nb_n, 256, 0, stream>>>(cnt, dinv, n);
    k_scan<<<1, 1024, 0, stream>>>(cnt, row_start, n);
    k_scatter<<<nb_e, 256, 0, stream>>>(srcv, dstv, row_start, cursor, dinv,
                                        csr_src, csr_coef, e);

    int nT = n * T_;
    k_embed<<<(nT + 15) / 16, 256, 0, stream>>>(x, We, be, xa, nT);

    int nb8 = (n + 7) / 8;
    const float* cur = xa;
    for (int i = 0; i < 3; i++) {
        float* nxt = (cur == xa) ? xb : xa;
        k_layer<<<nb8, 128, 0, stream>>>(cur, nxt, row_start, csr_src, csr_coef,
                                         dinv,
                                         wkp + (size_t)i * 3 * 4096,
                                         bkp + (size_t)i * 3 * 64,
                                         conv_b + (size_t)i * H_,
                                         bn_g + (size_t)i * H_, bn_b + (size_t)i * H_,
                                         bn_m + (size_t)i * H_, bn_v + (size_t)i * H_,
                                         n);
        cur = nxt;
    }

    k_attn<<<nb8, 128, 0, stream>>>(cur, ta_w1, ta_b1, ta_w2, ta_b2,
                                    fa_w1, fa_b1, fa_w2, fa_b2,
                                    ow1, ob1, ow2, ob2, (float*)d_out, n);
}

// Round 4
// 906.597 us; speedup vs baseline: 1.4068x; 1.1252x over previous
//
#include <hip/hip_runtime.h>
#include <cstddef>
#include <cstdint>

#define T_ 12
#define H_ 64
#define CIN_ 16
#define F_ 768          // H*T
#define PAD_ROW 772
#define BN_EPS 1e-5f

// ---------------- CSR build ----------------

__global__ void k_init(int* __restrict__ cnt, int* __restrict__ cursor, int n) {
    int i = blockIdx.x * 256 + threadIdx.x;
    if (i < n) { cnt[i] = 0; cursor[i] = 0; }
}

__global__ void k_count(const int* __restrict__ dstv, int* __restrict__ cnt, int e) {
    int i = blockIdx.x * 256 + threadIdx.x;
    if (i < e) atomicAdd(&cnt[dstv[i]], 1);
}

__global__ void k_dinv(const int* __restrict__ cnt, float* __restrict__ dinv, int n) {
    int i = blockIdx.x * 256 + threadIdx.x;
    if (i < n) dinv[i] = rsqrtf((float)(cnt[i] + 1));   // +1 self loop
}

__global__ void k_scan(const int* __restrict__ cnt, int* __restrict__ row_start, int n) {
    __shared__ int sd[1024];
    __shared__ int carry_s;
    if (threadIdx.x == 0) { carry_s = 0; row_start[0] = 0; }
    __syncthreads();
    for (int base = 0; base < n; base += 1024) {
        int i = base + (int)threadIdx.x;
        int v = (i < n) ? cnt[i] : 0;
        sd[threadIdx.x] = v;
        __syncthreads();
        for (int off = 1; off < 1024; off <<= 1) {
            int t = (threadIdx.x >= (unsigned)off) ? sd[threadIdx.x - off] : 0;
            __syncthreads();
            sd[threadIdx.x] += t;
            __syncthreads();
        }
        int carry = carry_s;
        if (i < n) row_start[i + 1] = carry + sd[threadIdx.x];
        __syncthreads();
        if (threadIdx.x == 1023) carry_s = carry + sd[1023];
        __syncthreads();
    }
}

__global__ void k_scatter(const int* __restrict__ srcv, const int* __restrict__ dstv,
                          const int* __restrict__ row_start, int* __restrict__ cursor,
                          const float* __restrict__ dinv, int* __restrict__ csr_src,
                          float* __restrict__ csr_coef, int e) {
    int i = blockIdx.x * 256 + threadIdx.x;
    if (i < e) {
        int d = dstv[i], s = srcv[i];
        int pos = atomicAdd(&cursor[d], 1);
        int idx = row_start[d] + pos;
        csr_src[idx]  = s;
        csr_coef[idx] = dinv[s] * dinv[d];
    }
}

// ---------------- weight prep: fold GCN W into conv planes ----------------

__global__ __launch_bounds__(256) void k_wprep(const float* __restrict__ gcn_W,
                                               const float* __restrict__ gcn_b,
                                               const float* __restrict__ conv_w,
                                               float* __restrict__ wkp,
                                               float* __restrict__ bkp) {
    int b = blockIdx.x;
    int l = b / 12, k = (b / 4) % 3, cq = b & 3;
    const float* Wg = gcn_W + (size_t)l * 4096;
    const float* cw = conv_w + (size_t)l * 12288;
    int tid = threadIdx.x;
#pragma unroll
    for (int j = 0; j < 4; j++) {
        int idx = j * 256 + tid;            // 0..1023
        int c = cq * 16 + (idx >> 6);
        int o = idx & 63;
        float acc = 0.f;
        for (int d = 0; d < 64; d++)
            acc += Wg[c * 64 + d] * cw[(size_t)(o * 64 + d) * 3 + k];
        wkp[(((size_t)l * 3 + k) * 64 + c) * 64 + o] = acc;
    }
    if (cq == 0 && tid < 64) {
        int o = tid;
        const float* gb = gcn_b + (size_t)l * 64;
        float acc = 0.f;
        for (int d = 0; d < 64; d++)
            acc += gb[d] * cw[(size_t)(o * 64 + d) * 3 + k];
        bkp[((size_t)l * 3 + k) * 64 + o] = acc;
    }
}

// ---------------- embedding ----------------

__global__ __launch_bounds__(256) void k_embed(const float* __restrict__ x,
                                               const float* __restrict__ We,
                                               const float* __restrict__ be,
                                               float* __restrict__ xst, int nT) {
    __shared__ float sW[CIN_ * H_];  // [c*64+h]
    __shared__ float sb[H_];
    for (int i = threadIdx.x; i < CIN_ * H_; i += 256) sW[i] = We[i];
    if (threadIdx.x < H_) sb[threadIdx.x] = be[threadIdx.x];
    __syncthreads();
    int h4  = threadIdx.x & 15;
    int ntl = threadIdx.x >> 4;
    int nt  = blockIdx.x * 16 + ntl;
    if (nt >= nT) return;
    const float4* xp = (const float4*)(x + (size_t)nt * CIN_);
    float4 xv4[4];
    xv4[0] = xp[0]; xv4[1] = xp[1]; xv4[2] = xp[2]; xv4[3] = xp[3];
    const float* xs = (const float*)xv4;
    float acc[4];
#pragma unroll
    for (int j = 0; j < 4; j++) acc[j] = sb[h4 * 4 + j];
#pragma unroll
    for (int c = 0; c < CIN_; c++) {
        float4 w = *(const float4*)&sW[c * H_ + h4 * 4];
        float xc = xs[c];
        acc[0] += xc * w.x; acc[1] += xc * w.y; acc[2] += xc * w.z; acc[3] += xc * w.w;
    }
    float4 o;
    o.x = fmaxf(acc[0], 0.f); o.y = fmaxf(acc[1], 0.f);
    o.z = fmaxf(acc[2], 0.f); o.w = fmaxf(acc[3], 0.f);
    *(float4*)&xst[(size_t)nt * H_ + h4 * 4] = o;
}

// ---------------- fused ST layer ----------------
// 8 nodes / 128 threads. LDS = sx only (24576 B) -> 6 blocks/CU (12 waves).
// Gather: per-wave 4-node split, edge loop unrolled x4 (12 dwordx4 in flight).
// Conv: x chunk read from LDS once per c, all 3 folded planes applied; weights
// streamed from global through L1 (16 KB/plane, resident).

#define FMA4(acc, cf, u) \
    acc.x += cf * u.x; acc.y += cf * u.y; acc.z += cf * u.z; acc.w += cf * u.w;

__global__ __launch_bounds__(128, 3) void k_layer(
        const float* __restrict__ xin, float* __restrict__ xout,
        const int* __restrict__ row_start, const int* __restrict__ csr_src,
        const float* __restrict__ csr_coef, const float* __restrict__ dinv,
        const float* __restrict__ wkp,    // [3][64][64] folded planes (this layer)
        const float* __restrict__ bkp,    // [3][64]
        const float* __restrict__ cb,
        const float* __restrict__ bng, const float* __restrict__ bnb,
        const float* __restrict__ bnm, const float* __restrict__ bnv,
        int n) {
    __shared__ float sx[8 * F_];     // 24576 B, swizzled chunks
    int tid = threadIdx.x;
    int n0 = blockIdx.x * 8;
    int wave = tid >> 6, lane = tid & 63;

    // ---- Phase A: gather/aggregate ----
    {
        int c0 = lane, c1 = lane + 64, c2 = lane + 128;
        for (int si = 0; si < 4; si++) {
            int s = wave * 4 + si;
            int nn = n0 + s; if (nn >= n) nn = n - 1;
            float dn = dinv[nn];
            float cs = dn * dn;
            const float4* xp = (const float4*)(xin + (size_t)nn * F_);
            float4 a0 = xp[c0], a1 = xp[c1], a2 = xp[c2];
            a0.x *= cs; a0.y *= cs; a0.z *= cs; a0.w *= cs;
            a1.x *= cs; a1.y *= cs; a1.z *= cs; a1.w *= cs;
            a2.x *= cs; a2.y *= cs; a2.z *= cs; a2.w *= cs;
            int e = row_start[nn], end = row_start[nn + 1];
            for (; e + 3 < end; e += 4) {
                int sA = csr_src[e],     sB = csr_src[e + 1];
                int sC = csr_src[e + 2], sD = csr_src[e + 3];
                float cA = csr_coef[e],     cB = csr_coef[e + 1];
                float cC = csr_coef[e + 2], cD = csr_coef[e + 3];
                const float4* pA = (const float4*)(xin + (size_t)sA * F_);
                const float4* pB = (const float4*)(xin + (size_t)sB * F_);
                const float4* pC = (const float4*)(xin + (size_t)sC * F_);
                const float4* pD = (const float4*)(xin + (size_t)sD * F_);
                float4 uA0 = pA[c0], uA1 = pA[c1], uA2 = pA[c2];
                float4 uB0 = pB[c0], uB1 = pB[c1], uB2 = pB[c2];
                float4 uC0 = pC[c0], uC1 = pC[c1], uC2 = pC[c2];
                float4 uD0 = pD[c0], uD1 = pD[c1], uD2 = pD[c2];
                FMA4(a0, cA, uA0) FMA4(a1, cA, uA1) FMA4(a2, cA, uA2)
                FMA4(a0, cB, uB0) FMA4(a1, cB, uB1) FMA4(a2, cB, uB2)
                FMA4(a0, cC, uC0) FMA4(a1, cC, uC1) FMA4(a2, cC, uC2)
                FMA4(a0, cD, uD0) FMA4(a1, cD, uD1) FMA4(a2, cD, uD2)
            }
            for (; e < end; e++) {
                int sA = csr_src[e];
                float cA = csr_coef[e];
                const float4* pA = (const float4*)(xin + (size_t)sA * F_);
                float4 uA0 = pA[c0], uA1 = pA[c1], uA2 = pA[c2];
                FMA4(a0, cA, uA0) FMA4(a1, cA, uA1) FMA4(a2, cA, uA2)
            }
            int s3 = s & 3;
            *(float4*)&sx[s * F_ + 4 * (c0 ^ s3)] = a0;
            *(float4*)&sx[s * F_ + 4 * (c1 ^ s3)] = a1;
            *(float4*)&sx[s * F_ + 4 * (c2 ^ s3)] = a2;
        }
    }
    __syncthreads();

    int s  = tid >> 4;         // 0..7
    int d4 = tid & 15;         // outputs o = d4*4 .. d4*4+3
    int s3 = s & 3;
    const float* xr = &sx[s * F_];
    const float4* w0p = (const float4*)wkp + d4;          // plane 0, + c*16
    const float4* w1p = (const float4*)(wkp + 4096) + d4; // plane 1
    const float4* w2p = (const float4*)(wkp + 8192) + d4; // plane 2

    // ---- Phase C: conv, all 3 planes per c ----
    float acc2[4][12];
#pragma unroll
    for (int j = 0; j < 4; j++)
#pragma unroll
        for (int t = 0; t < 12; t++) acc2[j][t] = 0.f;
    for (int c = 0; c < 64; c++) {
        float4 q0 = *(const float4*)&xr[4 * ((3 * c + 0) ^ s3)];
        float4 q1 = *(const float4*)&xr[4 * ((3 * c + 1) ^ s3)];
        float4 q2 = *(const float4*)&xr[4 * ((3 * c + 2) ^ s3)];
        float xv[12] = {q0.x, q0.y, q0.z, q0.w, q1.x, q1.y, q1.z, q1.w,
                        q2.x, q2.y, q2.z, q2.w};
        float4 w0 = w0p[c * 16];
        float4 w1 = w1p[c * 16];
        float4 w2 = w2p[c * 16];
        // k=0: out t gets xv[t-1] (t=1..11)
#pragma unroll
        for (int t = 1; t < 12; t++) {
            float xc = xv[t - 1];
            acc2[0][t] += w0.x * xc; acc2[1][t] += w0.y * xc;
            acc2[2][t] += w0.z * xc; acc2[3][t] += w0.w * xc;
        }
        // k=1: out t gets xv[t]
#pragma unroll
        for (int t = 0; t < 12; t++) {
            float xc = xv[t];
            acc2[0][t] += w1.x * xc; acc2[1][t] += w1.y * xc;
            acc2[2][t] += w1.z * xc; acc2[3][t] += w1.w * xc;
        }
        // k=2: out t gets xv[t+1] (t=0..10)
#pragma unroll
        for (int t = 0; t < 11; t++) {
            float xc = xv[t + 1];
            acc2[0][t] += w2.x * xc; acc2[1][t] += w2.y * xc;
            acc2[2][t] += w2.z * xc; acc2[3][t] += w2.w * xc;
        }
    }

    int nn = n0 + s;
    if (nn < n) {
        const float* rp = xin + (size_t)nn * F_;
        float* op = xout + (size_t)nn * F_;
#pragma unroll
        for (int j = 0; j < 4; j++) {
            int o = d4 * 4 + j;
            float scale = bng[o] * rsqrtf(bnv[o] + BN_EPS);
            float shift = bnb[o] - bnm[o] * scale;
            float bk0 = bkp[o], bk1 = bkp[64 + o], bk2 = bkp[128 + o];
            float b_all = cb[o] + bk0 + bk1 + bk2;
#pragma unroll
            for (int q = 0; q < 3; q++) {
                float4 r = *(const float4*)&rp[o * 12 + q * 4];
                float bias0 = b_all - ((q == 0) ? bk0 : 0.f);
                float bias3 = b_all - ((q == 2) ? bk2 : 0.f);
                float4 w;
                w.x = fmaxf((acc2[j][q * 4 + 0] + bias0) * scale + shift + r.x, 0.f);
                w.y = fmaxf((acc2[j][q * 4 + 1] + b_all) * scale + shift + r.y, 0.f);
                w.z = fmaxf((acc2[j][q * 4 + 2] + b_all) * scale + shift + r.z, 0.f);
                w.w = fmaxf((acc2[j][q * 4 + 3] + bias3) * scale + shift + r.w, 0.f);
                *(float4*)&op[o * 12 + q * 4] = w;
            }
        }
    }
}

// ---------------- dual attention + output MLP ----------------
// ta_w1 / ow1 (8 KB each) read through L1 instead of LDS -> ~28 KB LDS.

__global__ __launch_bounds__(128) void k_attn(const float* __restrict__ xst,
        const float* __restrict__ taw1, const float* __restrict__ tab1,
        const float* __restrict__ taw2, const float* __restrict__ tab2,
        const float* __restrict__ faw1, const float* __restrict__ fab1,
        const float* __restrict__ faw2, const float* __restrict__ fab2,
        const float* __restrict__ ow1, const float* __restrict__ ob1,
        const float* __restrict__ ow2, const float* __restrict__ ob2,
        float* __restrict__ out, int n) {
    __shared__ float sT[8 * PAD_ROW];       // [s][h*12+t]
    __shared__ float s_tab1[32], s_taw2[32], s_ob1[32], s_ow2[32];
    __shared__ float s_faw1[72], s_fab1[8], s_faw2[8];
    __shared__ float s_tw[8 * 12];
    __shared__ float s_xf[8 * 65];
    int tid = threadIdx.x;
    int n0 = blockIdx.x * 8;
    if (tid < 32) {
        s_tab1[tid] = tab1[tid]; s_taw2[tid] = taw2[tid];
        s_ob1[tid] = ob1[tid];   s_ow2[tid] = ow2[tid];
    }
    if (tid < 72) s_faw1[tid] = faw1[tid];
    if (tid < 6) { s_fab1[tid] = fab1[tid]; s_faw2[tid] = faw2[tid]; }
    float tb2 = tab2[0], fb2 = fab2[0], o_b2 = ob2[0];
    for (int i = tid; i < 8 * F_; i += 128) {
        int s = i / F_, j = i - s * F_;
        int t = j >> 6, hh = j & 63;
        int nn = n0 + s; if (nn >= n) nn = n - 1;
        sT[s * PAD_ROW + hh * 12 + t] = xst[(size_t)nn * F_ + j];
    }
    __syncthreads();

    int s = tid >> 4, m2 = tid & 15;
    {
        float a0[12], a1[12];
        float b0 = s_tab1[2 * m2], b1 = s_tab1[2 * m2 + 1];
#pragma unroll
        for (int t = 0; t < 12; t++) { a0[t] = b0; a1[t] = b1; }
        const float* xr = &sT[s * PAD_ROW];
        for (int hh = 0; hh < 64; hh++) {
            float4 q0 = *(const float4*)&xr[hh * 12];
            float4 q1 = *(const float4*)&xr[hh * 12 + 4];
            float4 q2 = *(const float4*)&xr[hh * 12 + 8];
            float xv[12] = {q0.x, q0.y, q0.z, q0.w, q1.x, q1.y, q1.z, q1.w, q2.x, q2.y, q2.z, q2.w};
            float2 wv = *(const float2*)&taw1[hh * 32 + 2 * m2];
#pragma unroll
            for (int t = 0; t < 12; t++) { a0[t] += wv.x * xv[t]; a1[t] += wv.y * xv[t]; }
        }
        float w20 = s_taw2[2 * m2], w21 = s_taw2[2 * m2 + 1];
#pragma unroll
        for (int t = 0; t < 12; t++) {
            float p = fmaxf(a0[t], 0.f) * w20 + fmaxf(a1[t], 0.f) * w21;
            p += __shfl_xor(p, 1); p += __shfl_xor(p, 2);
            p += __shfl_xor(p, 4); p += __shfl_xor(p, 8);
            if (m2 == 0) s_tw[s * 12 + t] = p + tb2;
        }
    }
    __syncthreads();

    int wave = tid >> 6, lane = tid & 63;
    for (int q = 0; q < 4; q++) {
        int ss = wave * 4 + q;
        float tw[12];
#pragma unroll
        for (int t = 0; t < 12; t++) tw[t] = s_tw[ss * 12 + t];
        float mx = tw[0];
#pragma unroll
        for (int t = 1; t < 12; t++) mx = fmaxf(mx, tw[t]);
        float sum = 0.f;
#pragma unroll
        for (int t = 0; t < 12; t++) { tw[t] = __expf(tw[t] - mx); sum += tw[t]; }
        float inv = 1.f / sum;
        const float* xr = &sT[ss * PAD_ROW + lane * 12];
        float4 q0 = *(const float4*)(xr);
        float4 q1 = *(const float4*)(xr + 4);
        float4 q2 = *(const float4*)(xr + 8);
        float xv[12] = {q0.x, q0.y, q0.z, q0.w, q1.x, q1.y, q1.z, q1.w, q2.x, q2.y, q2.z, q2.w};
        float xt[12];
#pragma unroll
        for (int t = 0; t < 12; t++) xt[t] = xv[t] * tw[t] * inv;
        float lf = fb2;
#pragma unroll
        for (int mm = 0; mm < 6; mm++) {
            float v = s_fab1[mm];
#pragma unroll
            for (int t = 0; t < 12; t++) v += xt[t] * s_faw1[t * 6 + mm];
            lf += fmaxf(v, 0.f) * s_faw2[mm];
        }
        float m2v = lf;
#pragma unroll
        for (int off = 32; off >= 1; off >>= 1) m2v = fmaxf(m2v, __shfl_xor(m2v, off));
        float e = __expf(lf - m2v);
        float se = e;
#pragma unroll
        for (int off = 32; off >= 1; off >>= 1) se += __shfl_xor(se, off);
        float fwv = e / se;
        float xs = 0.f;
#pragma unroll
        for (int t = 0; t < 12; t++) xs += xt[t];
        s_xf[ss * 65 + lane] = fwv * xs;
    }
    __syncthreads();

    {
        float v0 = s_ob1[2 * m2], v1 = s_ob1[2 * m2 + 1];
        const float* xfp = &s_xf[s * 65];
        for (int hh = 0; hh < 64; hh++) {
            float xv = xfp[hh];
            float2 wv = *(const float2*)&ow1[hh * 32 + 2 * m2];
            v0 += xv * wv.x;
            v1 += xv * wv.y;
        }
        float p = fmaxf(v0, 0.f) * s_ow2[2 * m2] + fmaxf(v1, 0.f) * s_ow2[2 * m2 + 1];
        p += __shfl_xor(p, 1); p += __shfl_xor(p, 2);
        p += __shfl_xor(p, 4); p += __shfl_xor(p, 8);
        if (m2 == 0 && n0 + s < n) out[n0 + s] = p + o_b2;
    }
}

// ---------------- launcher ----------------

extern "C" void kernel_launch(void* const* d_in, const int* in_sizes, int n_in,
                              void* d_out, int out_size, void* d_ws, size_t ws_size,
                              hipStream_t stream) {
    const float* x      = (const float*)d_in[0];
    const int*   ei     = (const int*)d_in[1];
    const float* We     = (const float*)d_in[2];
    const float* be     = (const float*)d_in[3];
    const float* gcn_W  = (const float*)d_in[4];
    const float* gcn_b  = (const float*)d_in[5];
    const float* conv_w = (const float*)d_in[6];
    const float* conv_b = (const float*)d_in[7];
    const float* bn_g   = (const float*)d_in[8];
    const float* bn_b   = (const float*)d_in[9];
    const float* bn_m   = (const float*)d_in[10];
    const float* bn_v   = (const float*)d_in[11];
    const float* ta_w1  = (const float*)d_in[12];
    const float* ta_b1  = (const float*)d_in[13];
    const float* ta_w2  = (const float*)d_in[14];
    const float* ta_b2  = (const float*)d_in[15];
    const float* fa_w1  = (const float*)d_in[16];
    const float* fa_b1  = (const float*)d_in[17];
    const float* fa_w2  = (const float*)d_in[18];
    const float* fa_b2  = (const float*)d_in[19];
    const float* ow1    = (const float*)d_in[20];
    const float* ob1    = (const float*)d_in[21];
    const float* ow2    = (const float*)d_in[22];
    const float* ob2    = (const float*)d_in[23];

    int n = in_sizes[0] / (T_ * CIN_);
    int e = in_sizes[1] / 2;
    const int* srcv = ei;
    const int* dstv = ei + e;

    char* p = (char*)d_ws;
    auto take = [&](size_t bytes) -> void* {
        void* r = (void*)p;
        p += (bytes + 255) & ~(size_t)255;
        return r;
    };
    int*   cnt       = (int*)take((size_t)n * 4);
    int*   cursor    = (int*)take((size_t)n * 4);
    int*   row_start = (int*)take(((size_t)n + 1) * 4);
    float* dinv      = (float*)take((size_t)n * 4);
    int*   csr_src   = (int*)take((size_t)e * 4);
    float* csr_coef  = (float*)take((size_t)e * 4);
    float* wkp       = (float*)take((size_t)3 * 3 * 64 * 64 * 4);
    float* bkp       = (float*)take((size_t)3 * 3 * 64 * 4);
    float* xa        = (float*)take((size_t)n * F_ * 4);
    float* xb        = (float*)take((size_t)n * F_ * 4);

    int nb_n = (n + 255) / 256;
    int nb_e = (e + 255) / 256;

    k_wprep<<<36, 256, 0, stream>>>(gcn_W, gcn_b, conv_w, wkp, bkp);
    k_init<<<nb_n, 256, 0, stream>>>(cnt, cursor, n);
    k_count<<<nb_e, 256, 0, stream>>>(dstv, cnt, e);
    k_dinv<<<nb_n, 256, 0, stream>>>(cnt, dinv, n);
    k_scan<<<1, 1024, 0, stream>>>(cnt, row_start, n);
    k_scatter<<<nb_e, 256, 0, stream>>>(srcv, dstv, row_start, cursor, dinv,
                                        csr_src, csr_coef, e);

    int nT = n * T_;
    k_embed<<<(nT + 15) / 16, 256, 0, stream>>>(x, We, be, xa, nT);

    int nb8 = (n + 7) / 8;
    const float* cur = xa;
    for (int i = 0; i < 3; i++) {
        float* nxt = (cur == xa) ? xb : xa;
        k_layer<<<nb8, 128, 0, stream>>>(cur, nxt, row_start, csr_src, csr_coef,
                                         dinv,
                                         wkp + (size_t)i * 3 * 4096,
                                         bkp + (size_t)i * 3 * 64,
                                         conv_b + (size_t)i * H_,
                                         bn_g + (size_t)i * H_, bn_b + (size_t)i * H_,
                                         bn_m + (size_t)i * H_, bn_v + (size_t)i * H_,
                                         n);
        cur = nxt;
    }

    k_attn<<<nb8, 128, 0, stream>>>(cur, ta_w1, ta_b1, ta_w2, ta_b2,
                                    fa_w1, fa_b1, fa_w2, fa_b2,
                                    ow1, ob1, ow2, ob2, (float*)d_out, n);
}

// Round 5
// 751.178 us; speedup vs baseline: 1.6979x; 1.2069x over previous
//
#include <hip/hip_runtime.h>
#include <cstddef>
#include <cstdint>

#define T_ 12
#define H_ 64
#define CIN_ 16
#define F_ 768          // H*T
#define PAD_ROW 772
#define BN_EPS 1e-5f
#define ECAP 128        // staged edges per wave

// fp32 -> bf16 round-to-nearest-even
__device__ __forceinline__ unsigned short f2bf(float f) {
    unsigned u = __float_as_uint(f);
    unsigned r = (u + 0x7FFFu + ((u >> 16) & 1u)) >> 16;
    return (unsigned short)r;
}

// ---------------- CSR build ----------------

__global__ void k_init(int* __restrict__ cnt, int* __restrict__ cursor, int n) {
    int i = blockIdx.x * 256 + threadIdx.x;
    if (i < n) { cnt[i] = 0; cursor[i] = 0; }
}

__global__ void k_count(const int* __restrict__ dstv, int* __restrict__ cnt, int e) {
    int i = blockIdx.x * 256 + threadIdx.x;
    if (i < e) atomicAdd(&cnt[dstv[i]], 1);
}

// hierarchical exclusive scan: scan1 (per-1024-block) -> scan2 (block sums) -> scan3 (+dinv)
__global__ __launch_bounds__(1024) void k_scan1(const int* __restrict__ cnt,
                                                int* __restrict__ row_local,
                                                int* __restrict__ bsum, int n) {
    __shared__ int sd[1024];
    int tid = threadIdx.x;
    int i = blockIdx.x * 1024 + tid;
    int v = (i < n) ? cnt[i] : 0;
    sd[tid] = v;
    __syncthreads();
    for (int off = 1; off < 1024; off <<= 1) {
        int t = (tid >= off) ? sd[tid - off] : 0;
        __syncthreads();
        sd[tid] += t;
        __syncthreads();
    }
    if (i < n) row_local[i] = sd[tid] - v;   // exclusive within block
    if (tid == 1023) bsum[blockIdx.x] = sd[1023];
}

__global__ __launch_bounds__(64) void k_scan2(const int* __restrict__ bsum,
                                              int* __restrict__ boff, int nb,
                                              int* __restrict__ row_start, int n) {
    int lane = threadIdx.x;
    int orig = (lane < nb) ? bsum[lane] : 0;
    int v = orig;
    for (int off = 1; off < 64; off <<= 1) {
        int t = __shfl_up(v, off);
        if (lane >= off) v += t;
    }
    if (lane < nb) boff[lane] = v - orig;
    if (lane == 63) row_start[n] = v;
}

__global__ __launch_bounds__(1024) void k_scan3(const int* __restrict__ row_local,
                                                const int* __restrict__ boff,
                                                const int* __restrict__ cnt,
                                                int* __restrict__ row_start,
                                                float* __restrict__ dinv, int n) {
    int i = blockIdx.x * 1024 + threadIdx.x;
    if (i < n) {
        row_start[i] = row_local[i] + boff[blockIdx.x];
        dinv[i] = rsqrtf((float)(cnt[i] + 1));
    }
}

__global__ void k_scatter(const int* __restrict__ srcv, const int* __restrict__ dstv,
                          const int* __restrict__ row_start, int* __restrict__ cursor,
                          const float* __restrict__ dinv, int* __restrict__ csr_src,
                          float* __restrict__ csr_coef, int e) {
    int i = blockIdx.x * 256 + threadIdx.x;
    if (i < e) {
        int d = dstv[i], s = srcv[i];
        int pos = atomicAdd(&cursor[d], 1);
        int idx = row_start[d] + pos;
        csr_src[idx]  = s;
        csr_coef[idx] = dinv[s] * dinv[d];
    }
}

// ---------------- weight prep: fold GCN W into conv planes ----------------

__global__ __launch_bounds__(256) void k_wprep(const float* __restrict__ gcn_W,
                                               const float* __restrict__ gcn_b,
                                               const float* __restrict__ conv_w,
                                               float* __restrict__ wkp,
                                               float* __restrict__ bkp) {
    int b = blockIdx.x;
    int l = b / 12, k = (b / 4) % 3, cq = b & 3;
    const float* Wg = gcn_W + (size_t)l * 4096;
    const float* cw = conv_w + (size_t)l * 12288;
    int tid = threadIdx.x;
#pragma unroll
    for (int j = 0; j < 4; j++) {
        int idx = j * 256 + tid;            // 0..1023
        int c = cq * 16 + (idx >> 6);
        int o = idx & 63;
        float acc = 0.f;
        for (int d = 0; d < 64; d++)
            acc += Wg[c * 64 + d] * cw[(size_t)(o * 64 + d) * 3 + k];
        wkp[(((size_t)l * 3 + k) * 64 + c) * 64 + o] = acc;
    }
    if (cq == 0 && tid < 64) {
        int o = tid;
        const float* gb = gcn_b + (size_t)l * 64;
        float acc = 0.f;
        for (int d = 0; d < 64; d++)
            acc += gb[d] * cw[(size_t)(o * 64 + d) * 3 + k];
        bkp[((size_t)l * 3 + k) * 64 + o] = acc;
    }
}

// ---------------- embedding (writes fp32 + bf16 copies) ----------------

__global__ __launch_bounds__(256) void k_embed(const float* __restrict__ x,
                                               const float* __restrict__ We,
                                               const float* __restrict__ be,
                                               float* __restrict__ xst,
                                               unsigned short* __restrict__ xbf,
                                               int nT) {
    __shared__ float sW[CIN_ * H_];  // [c*64+h]
    __shared__ float sb[H_];
    for (int i = threadIdx.x; i < CIN_ * H_; i += 256) sW[i] = We[i];
    if (threadIdx.x < H_) sb[threadIdx.x] = be[threadIdx.x];
    __syncthreads();
    int h4  = threadIdx.x & 15;
    int ntl = threadIdx.x >> 4;
    int nt  = blockIdx.x * 16 + ntl;
    if (nt >= nT) return;
    const float4* xp = (const float4*)(x + (size_t)nt * CIN_);
    float4 xv4[4];
    xv4[0] = xp[0]; xv4[1] = xp[1]; xv4[2] = xp[2]; xv4[3] = xp[3];
    const float* xs = (const float*)xv4;
    float acc[4];
#pragma unroll
    for (int j = 0; j < 4; j++) acc[j] = sb[h4 * 4 + j];
#pragma unroll
    for (int c = 0; c < CIN_; c++) {
        float4 w = *(const float4*)&sW[c * H_ + h4 * 4];
        float xc = xs[c];
        acc[0] += xc * w.x; acc[1] += xc * w.y; acc[2] += xc * w.z; acc[3] += xc * w.w;
    }
    float4 o;
    o.x = fmaxf(acc[0], 0.f); o.y = fmaxf(acc[1], 0.f);
    o.z = fmaxf(acc[2], 0.f); o.w = fmaxf(acc[3], 0.f);
    *(float4*)&xst[(size_t)nt * H_ + h4 * 4] = o;
    ushort4 h;
    h.x = f2bf(o.x); h.y = f2bf(o.y); h.z = f2bf(o.z); h.w = f2bf(o.w);
    *(ushort4*)&xbf[(size_t)nt * H_ + h4 * 4] = h;
}

// ---------------- fused ST layer ----------------
// 8 nodes / 128 threads. LDS = sx (24576) + edge buf (2048) -> 6 blocks/CU.
// Phase A: per-wave 4-node split. Edge (src,coef) pairs staged into LDS
// (coalesced, one latency), then gather streams bf16 neighbor rows (8 B/lane
// chunks), x4 edge unroll. Self contribution stays fp32.
// Phase C: conv from LDS (fp32), folded planes via L1.

#define FMA4(acc, cf, u) \
    acc.x += cf * u.x; acc.y += cf * u.y; acc.z += cf * u.z; acc.w += cf * u.w;
#define BFMA(acc, cf, u) { \
    acc.x += cf * __uint_as_float(((unsigned)(u).x) << 16); \
    acc.y += cf * __uint_as_float(((unsigned)(u).y) << 16); \
    acc.z += cf * __uint_as_float(((unsigned)(u).z) << 16); \
    acc.w += cf * __uint_as_float(((unsigned)(u).w) << 16); }

__global__ __launch_bounds__(128, 3) void k_layer(
        const float* __restrict__ xin, const unsigned short* __restrict__ xbf,
        float* __restrict__ xout, unsigned short* __restrict__ xbfout,
        const int* __restrict__ row_start, const int* __restrict__ csr_src,
        const float* __restrict__ csr_coef, const float* __restrict__ dinv,
        const float* __restrict__ wkp,    // [3][64][64] folded planes
        const float* __restrict__ bkp,    // [3][64]
        const float* __restrict__ cb,
        const float* __restrict__ bng, const float* __restrict__ bnb,
        const float* __restrict__ bnm, const float* __restrict__ bnv,
        int n) {
    __shared__ float sx[8 * F_];         // 24576 B
    __shared__ int   se[2 * ECAP * 2];   // 2048 B: per-wave (src,coef) pairs
    int tid = threadIdx.x;
    int n0 = blockIdx.x * 8;
    int wave = tid >> 6, lane = tid & 63;
    int wbase = wave * (ECAP * 2);

    // ---- stage edge lists for this wave's 4 nodes ----
    int begs[4], cnts[4], stgs[4], epos[4];
    {
        int pos = 0;
#pragma unroll
        for (int si = 0; si < 4; si++) {
            int nn = n0 + wave * 4 + si; if (nn >= n) nn = n - 1;
            int beg = row_start[nn], end = row_start[nn + 1];
            int cnt = end - beg;
            int stg = min(cnt, ECAP - pos);
            for (int i = lane; i < stg; i += 64) {
                se[wbase + (pos + i) * 2]     = csr_src[beg + i];
                se[wbase + (pos + i) * 2 + 1] = __float_as_int(csr_coef[beg + i]);
            }
            begs[si] = beg; cnts[si] = cnt; stgs[si] = stg; epos[si] = pos;
            pos += stg;
        }
    }

    // ---- Phase A: gather/aggregate ----
    {
        int c0 = lane, c1 = lane + 64, c2 = lane + 128;   // 4-elem chunks
#pragma unroll
        for (int si = 0; si < 4; si++) {
            int s = wave * 4 + si;
            int nn = n0 + s; if (nn >= n) nn = n - 1;
            float dn = dinv[nn];
            float cs = dn * dn;
            const float4* xp = (const float4*)(xin + (size_t)nn * F_);
            float4 a0 = xp[c0], a1 = xp[c1], a2 = xp[c2];
            a0.x *= cs; a0.y *= cs; a0.z *= cs; a0.w *= cs;
            a1.x *= cs; a1.y *= cs; a1.z *= cs; a1.w *= cs;
            a2.x *= cs; a2.y *= cs; a2.z *= cs; a2.w *= cs;
            int cnt = stgs[si];
            int base = wbase + epos[si] * 2;
            int e = 0;
            for (; e + 3 < cnt; e += 4) {
                int2 p0 = *(const int2*)&se[base + e * 2];
                int2 p1 = *(const int2*)&se[base + e * 2 + 2];
                int2 p2 = *(const int2*)&se[base + e * 2 + 4];
                int2 p3 = *(const int2*)&se[base + e * 2 + 6];
                const ushort4* pA = (const ushort4*)(xbf + (size_t)p0.x * F_);
                const ushort4* pB = (const ushort4*)(xbf + (size_t)p1.x * F_);
                const ushort4* pC = (const ushort4*)(xbf + (size_t)p2.x * F_);
                const ushort4* pD = (const ushort4*)(xbf + (size_t)p3.x * F_);
                ushort4 uA0 = pA[c0], uA1 = pA[c1], uA2 = pA[c2];
                ushort4 uB0 = pB[c0], uB1 = pB[c1], uB2 = pB[c2];
                ushort4 uC0 = pC[c0], uC1 = pC[c1], uC2 = pC[c2];
                ushort4 uD0 = pD[c0], uD1 = pD[c1], uD2 = pD[c2];
                float cA = __int_as_float(p0.y), cB = __int_as_float(p1.y);
                float cC = __int_as_float(p2.y), cD = __int_as_float(p3.y);
                BFMA(a0, cA, uA0) BFMA(a1, cA, uA1) BFMA(a2, cA, uA2)
                BFMA(a0, cB, uB0) BFMA(a1, cB, uB1) BFMA(a2, cB, uB2)
                BFMA(a0, cC, uC0) BFMA(a1, cC, uC1) BFMA(a2, cC, uC2)
                BFMA(a0, cD, uD0) BFMA(a1, cD, uD1) BFMA(a2, cD, uD2)
            }
            for (; e < cnt; e++) {
                int2 p0 = *(const int2*)&se[base + e * 2];
                const ushort4* pA = (const ushort4*)(xbf + (size_t)p0.x * F_);
                ushort4 uA0 = pA[c0], uA1 = pA[c1], uA2 = pA[c2];
                float cA = __int_as_float(p0.y);
                BFMA(a0, cA, uA0) BFMA(a1, cA, uA1) BFMA(a2, cA, uA2)
            }
            // fallback for edges beyond LDS capacity (essentially never)
            for (int g = begs[si] + stgs[si]; g < begs[si] + cnts[si]; g++) {
                int srcI = csr_src[g];
                float cf = csr_coef[g];
                const ushort4* pA = (const ushort4*)(xbf + (size_t)srcI * F_);
                ushort4 uA0 = pA[c0], uA1 = pA[c1], uA2 = pA[c2];
                BFMA(a0, cf, uA0) BFMA(a1, cf, uA1) BFMA(a2, cf, uA2)
            }
            int s3 = s & 3;
            *(float4*)&sx[s * F_ + 4 * (c0 ^ s3)] = a0;
            *(float4*)&sx[s * F_ + 4 * (c1 ^ s3)] = a1;
            *(float4*)&sx[s * F_ + 4 * (c2 ^ s3)] = a2;
        }
    }
    __syncthreads();

    int s  = tid >> 4;         // 0..7
    int d4 = tid & 15;         // outputs o = d4*4 .. d4*4+3
    int s3 = s & 3;
    const float* xr = &sx[s * F_];
    const float4* w0p = (const float4*)wkp + d4;          // plane 0, + c*16
    const float4* w1p = (const float4*)(wkp + 4096) + d4; // plane 1
    const float4* w2p = (const float4*)(wkp + 8192) + d4; // plane 2

    // ---- Phase C: conv, all 3 planes per c ----
    float acc2[4][12];
#pragma unroll
    for (int j = 0; j < 4; j++)
#pragma unroll
        for (int t = 0; t < 12; t++) acc2[j][t] = 0.f;
    for (int c = 0; c < 64; c++) {
        float4 q0 = *(const float4*)&xr[4 * ((3 * c + 0) ^ s3)];
        float4 q1 = *(const float4*)&xr[4 * ((3 * c + 1) ^ s3)];
        float4 q2 = *(const float4*)&xr[4 * ((3 * c + 2) ^ s3)];
        float xv[12] = {q0.x, q0.y, q0.z, q0.w, q1.x, q1.y, q1.z, q1.w,
                        q2.x, q2.y, q2.z, q2.w};
        float4 w0 = w0p[c * 16];
        float4 w1 = w1p[c * 16];
        float4 w2 = w2p[c * 16];
#pragma unroll
        for (int t = 1; t < 12; t++) {
            float xc = xv[t - 1];
            acc2[0][t] += w0.x * xc; acc2[1][t] += w0.y * xc;
            acc2[2][t] += w0.z * xc; acc2[3][t] += w0.w * xc;
        }
#pragma unroll
        for (int t = 0; t < 12; t++) {
            float xc = xv[t];
            acc2[0][t] += w1.x * xc; acc2[1][t] += w1.y * xc;
            acc2[2][t] += w1.z * xc; acc2[3][t] += w1.w * xc;
        }
#pragma unroll
        for (int t = 0; t < 11; t++) {
            float xc = xv[t + 1];
            acc2[0][t] += w2.x * xc; acc2[1][t] += w2.y * xc;
            acc2[2][t] += w2.z * xc; acc2[3][t] += w2.w * xc;
        }
    }

    int nn = n0 + s;
    if (nn < n) {
        const float* rp = xin + (size_t)nn * F_;
        float* op = xout + (size_t)nn * F_;
        unsigned short* ob = xbfout + (size_t)nn * F_;
#pragma unroll
        for (int j = 0; j < 4; j++) {
            int o = d4 * 4 + j;
            float scale = bng[o] * rsqrtf(bnv[o] + BN_EPS);
            float shift = bnb[o] - bnm[o] * scale;
            float bk0 = bkp[o], bk1 = bkp[64 + o], bk2 = bkp[128 + o];
            float b_all = cb[o] + bk0 + bk1 + bk2;
#pragma unroll
            for (int q = 0; q < 3; q++) {
                float4 r = *(const float4*)&rp[o * 12 + q * 4];
                float bias0 = b_all - ((q == 0) ? bk0 : 0.f);
                float bias3 = b_all - ((q == 2) ? bk2 : 0.f);
                float4 w;
                w.x = fmaxf((acc2[j][q * 4 + 0] + bias0) * scale + shift + r.x, 0.f);
                w.y = fmaxf((acc2[j][q * 4 + 1] + b_all) * scale + shift + r.y, 0.f);
                w.z = fmaxf((acc2[j][q * 4 + 2] + b_all) * scale + shift + r.z, 0.f);
                w.w = fmaxf((acc2[j][q * 4 + 3] + bias3) * scale + shift + r.w, 0.f);
                *(float4*)&op[o * 12 + q * 4] = w;
                ushort4 hb;
                hb.x = f2bf(w.x); hb.y = f2bf(w.y);
                hb.z = f2bf(w.z); hb.w = f2bf(w.w);
                *(ushort4*)&ob[o * 12 + q * 4] = hb;
            }
        }
    }
}

// ---------------- dual attention + output MLP ----------------

__global__ __launch_bounds__(128) void k_attn(const float* __restrict__ xst,
        const float* __restrict__ taw1, const float* __restrict__ tab1,
        const float* __restrict__ taw2, const float* __restrict__ tab2,
        const float* __restrict__ faw1, const float* __restrict__ fab1,
        const float* __restrict__ faw2, const float* __restrict__ fab2,
        const float* __restrict__ ow1, const float* __restrict__ ob1,
        const float* __restrict__ ow2, const float* __restrict__ ob2,
        float* __restrict__ out, int n) {
    __shared__ float sT[8 * PAD_ROW];       // [s][h*12+t]
    __shared__ float s_tab1[32], s_taw2[32], s_ob1[32], s_ow2[32];
    __shared__ float s_faw1[72], s_fab1[8], s_faw2[8];
    __shared__ float s_tw[8 * 12];
    __shared__ float s_xf[8 * 65];
    int tid = threadIdx.x;
    int n0 = blockIdx.x * 8;
    if (tid < 32) {
        s_tab1[tid] = tab1[tid]; s_taw2[tid] = taw2[tid];
        s_ob1[tid] = ob1[tid];   s_ow2[tid] = ow2[tid];
    }
    if (tid < 72) s_faw1[tid] = faw1[tid];
    if (tid < 6) { s_fab1[tid] = fab1[tid]; s_faw2[tid] = faw2[tid]; }
    float tb2 = tab2[0], fb2 = fab2[0], o_b2 = ob2[0];
    for (int i = tid; i < 8 * F_; i += 128) {
        int s = i / F_, j = i - s * F_;
        int t = j >> 6, hh = j & 63;
        int nn = n0 + s; if (nn >= n) nn = n - 1;
        sT[s * PAD_ROW + hh * 12 + t] = xst[(size_t)nn * F_ + j];
    }
    __syncthreads();

    int s = tid >> 4, m2 = tid & 15;
    {
        float a0[12], a1[12];
        float b0 = s_tab1[2 * m2], b1 = s_tab1[2 * m2 + 1];
#pragma unroll
        for (int t = 0; t < 12; t++) { a0[t] = b0; a1[t] = b1; }
        const float* xr = &sT[s * PAD_ROW];
        for (int hh = 0; hh < 64; hh++) {
            float4 q0 = *(const float4*)&xr[hh * 12];
            float4 q1 = *(const float4*)&xr[hh * 12 + 4];
            float4 q2 = *(const float4*)&xr[hh * 12 + 8];
            float xv[12] = {q0.x, q0.y, q0.z, q0.w, q1.x, q1.y, q1.z, q1.w, q2.x, q2.y, q2.z, q2.w};
            float2 wv = *(const float2*)&taw1[hh * 32 + 2 * m2];
#pragma unroll
            for (int t = 0; t < 12; t++) { a0[t] += wv.x * xv[t]; a1[t] += wv.y * xv[t]; }
        }
        float w20 = s_taw2[2 * m2], w21 = s_taw2[2 * m2 + 1];
#pragma unroll
        for (int t = 0; t < 12; t++) {
            float p = fmaxf(a0[t], 0.f) * w20 + fmaxf(a1[t], 0.f) * w21;
            p += __shfl_xor(p, 1); p += __shfl_xor(p, 2);
            p += __shfl_xor(p, 4); p += __shfl_xor(p, 8);
            if (m2 == 0) s_tw[s * 12 + t] = p + tb2;
        }
    }
    __syncthreads();

    int wave = tid >> 6, lane = tid & 63;
    for (int q = 0; q < 4; q++) {
        int ss = wave * 4 + q;
        float tw[12];
#pragma unroll
        for (int t = 0; t < 12; t++) tw[t] = s_tw[ss * 12 + t];
        float mx = tw[0];
#pragma unroll
        for (int t = 1; t < 12; t++) mx = fmaxf(mx, tw[t]);
        float sum = 0.f;
#pragma unroll
        for (int t = 0; t < 12; t++) { tw[t] = __expf(tw[t] - mx); sum += tw[t]; }
        float inv = 1.f / sum;
        const float* xr = &sT[ss * PAD_ROW + lane * 12];
        float4 q0 = *(const float4*)(xr);
        float4 q1 = *(const float4*)(xr + 4);
        float4 q2 = *(const float4*)(xr + 8);
        float xv[12] = {q0.x, q0.y, q0.z, q0.w, q1.x, q1.y, q1.z, q1.w, q2.x, q2.y, q2.z, q2.w};
        float xt[12];
#pragma unroll
        for (int t = 0; t < 12; t++) xt[t] = xv[t] * tw[t] * inv;
        float lf = fb2;
#pragma unroll
        for (int mm = 0; mm < 6; mm++) {
            float v = s_fab1[mm];
#pragma unroll
            for (int t = 0; t < 12; t++) v += xt[t] * s_faw1[t * 6 + mm];
            lf += fmaxf(v, 0.f) * s_faw2[mm];
        }
        float m2v = lf;
#pragma unroll
        for (int off = 32; off >= 1; off >>= 1) m2v = fmaxf(m2v, __shfl_xor(m2v, off));
        float e = __expf(lf - m2v);
        float se = e;
#pragma unroll
        for (int off = 32; off >= 1; off >>= 1) se += __shfl_xor(se, off);
        float fwv = e / se;
        float xs = 0.f;
#pragma unroll
        for (int t = 0; t < 12; t++) xs += xt[t];
        s_xf[ss * 65 + lane] = fwv * xs;
    }
    __syncthreads();

    {
        float v0 = s_ob1[2 * m2], v1 = s_ob1[2 * m2 + 1];
        const float* xfp = &s_xf[s * 65];
        for (int hh = 0; hh < 64; hh++) {
            float xv = xfp[hh];
            float2 wv = *(const float2*)&ow1[hh * 32 + 2 * m2];
            v0 += xv * wv.x;
            v1 += xv * wv.y;
        }
        float p = fmaxf(v0, 0.f) * s_ow2[2 * m2] + fmaxf(v1, 0.f) * s_ow2[2 * m2 + 1];
        p += __shfl_xor(p, 1); p += __shfl_xor(p, 2);
        p += __shfl_xor(p, 4); p += __shfl_xor(p, 8);
        if (m2 == 0 && n0 + s < n) out[n0 + s] = p + o_b2;
    }
}

// ---------------- launcher ----------------

extern "C" void kernel_launch(void* const* d_in, const int* in_sizes, int n_in,
                              void* d_out, int out_size, void* d_ws, size_t ws_size,
                              hipStream_t stream) {
    const float* x      = (const float*)d_in[0];
    const int*   ei     = (const int*)d_in[1];
    const float* We     = (const float*)d_in[2];
    const float* be     = (const float*)d_in[3];
    const float* gcn_W  = (const float*)d_in[4];
    const float* gcn_b  = (const float*)d_in[5];
    const float* conv_w = (const float*)d_in[6];
    const float* conv_b = (const float*)d_in[7];
    const float* bn_g   = (const float*)d_in[8];
    const float* bn_b   = (const float*)d_in[9];
    const float* bn_m   = (const float*)d_in[10];
    const float* bn_v   = (const float*)d_in[11];
    const float* ta_w1  = (const float*)d_in[12];
    const float* ta_b1  = (const float*)d_in[13];
    const float* ta_w2  = (const float*)d_in[14];
    const float* ta_b2  = (const float*)d_in[15];
    const float* fa_w1  = (const float*)d_in[16];
    const float* fa_b1  = (const float*)d_in[17];
    const float* fa_w2  = (const float*)d_in[18];
    const float* fa_b2  = (const float*)d_in[19];
    const float* ow1    = (const float*)d_in[20];
    const float* ob1    = (const float*)d_in[21];
    const float* ow2    = (const float*)d_in[22];
    const float* ob2    = (const float*)d_in[23];

    int n = in_sizes[0] / (T_ * CIN_);
    int e = in_sizes[1] / 2;
    const int* srcv = ei;
    const int* dstv = ei + e;

    char* p = (char*)d_ws;
    auto take = [&](size_t bytes) -> void* {
        void* r = (void*)p;
        p += (bytes + 255) & ~(size_t)255;
        return r;
    };
    int*   cnt       = (int*)take((size_t)n * 4);
    int*   cursor    = (int*)take((size_t)n * 4);
    int*   row_start = (int*)take(((size_t)n + 1) * 4);
    int*   row_local = (int*)take((size_t)n * 4);
    int*   bsum      = (int*)take(1024 * 4);
    int*   boff      = (int*)take(1024 * 4);
    float* dinv      = (float*)take((size_t)n * 4);
    int*   csr_src   = (int*)take((size_t)e * 4);
    float* csr_coef  = (float*)take((size_t)e * 4);
    float* wkp       = (float*)take((size_t)3 * 3 * 64 * 64 * 4);
    float* bkp       = (float*)take((size_t)3 * 3 * 64 * 4);
    float* xa        = (float*)take((size_t)n * F_ * 4);
    float* xb        = (float*)take((size_t)n * F_ * 4);
    unsigned short* xabf = (unsigned short*)take((size_t)n * F_ * 2);
    unsigned short* xbbf = (unsigned short*)take((size_t)n * F_ * 2);

    int nb_n = (n + 255) / 256;
    int nb_e = (e + 255) / 256;
    int nb_s = (n + 1023) / 1024;

    k_wprep<<<36, 256, 0, stream>>>(gcn_W, gcn_b, conv_w, wkp, bkp);
    k_init<<<nb_n, 256, 0, stream>>>(cnt, cursor, n);
    k_count<<<nb_e, 256, 0, stream>>>(dstv, cnt, e);
    k_scan1<<<nb_s, 1024, 0, stream>>>(cnt, row_local, bsum, n);
    k_scan2<<<1, 64, 0, stream>>>(bsum, boff, nb_s, row_start, n);
    k_scan3<<<nb_s, 1024, 0, stream>>>(row_local, boff, cnt, row_start, dinv, n);
    k_scatter<<<nb_e, 256, 0, stream>>>(srcv, dstv, row_start, cursor, dinv,
                                        csr_src, csr_coef, e);

    int nT = n * T_;
    k_embed<<<(nT + 15) / 16, 256, 0, stream>>>(x, We, be, xa, xabf, nT);

    int nb8 = (n + 7) / 8;
    const float* cur = xa;
    const unsigned short* curbf = xabf;
    for (int i = 0; i < 3; i++) {
        float* nxt = (cur == xa) ? xb : xa;
        unsigned short* nxtbf = (cur == xa) ? xbbf : xabf;
        k_layer<<<nb8, 128, 0, stream>>>(cur, curbf, nxt, nxtbf,
                                         row_start, csr_src, csr_coef, dinv,
                                         wkp + (size_t)i * 3 * 4096,
                                         bkp + (size_t)i * 3 * 64,
                                         conv_b + (size_t)i * H_,
                                         bn_g + (size_t)i * H_, bn_b + (size_t)i * H_,
                                         bn_m + (size_t)i * H_, bn_v + (size_t)i * H_,
                                         n);
        cur = nxt; curbf = nxtbf;
    }

    k_attn<<<nb8, 128, 0, stream>>>(cur, ta_w1, ta_b1, ta_w2, ta_b2,
                                    fa_w1, fa_b1, fa_w2, fa_b2,
                                    ow1, ob1, ow2, ob2, (float*)d_out, n);
}

// Round 6
// 677.582 us; speedup vs baseline: 1.8823x; 1.1086x over previous
//
#include <hip/hip_runtime.h>
#include <cstddef>
#include <cstdint>

#define T_ 12
#define H_ 64
#define CIN_ 16
#define F_ 768          // H*T
#define PAD_ROW 772
#define BN_EPS 1e-5f
#define ECAP 80         // staged edges per wave (2 nodes, mean deg 16 -> ~32)

// fp32 -> bf16 round-to-nearest-even
__device__ __forceinline__ unsigned short f2bf(float f) {
    unsigned u = __float_as_uint(f);
    unsigned r = (u + 0x7FFFu + ((u >> 16) & 1u)) >> 16;
    return (unsigned short)r;
}
__device__ __forceinline__ float bf2f(unsigned short h) {
    return __uint_as_float(((unsigned)h) << 16);
}

// ---------------- CSR build ----------------

__global__ void k_init(int* __restrict__ cnt, int* __restrict__ cursor, int n) {
    int i = blockIdx.x * 256 + threadIdx.x;
    if (i < n) { cnt[i] = 0; cursor[i] = 0; }
}

__global__ void k_count(const int* __restrict__ dstv, int* __restrict__ cnt, int e) {
    int i = blockIdx.x * 256 + threadIdx.x;
    if (i < e) atomicAdd(&cnt[dstv[i]], 1);
}

__global__ __launch_bounds__(1024) void k_scan1(const int* __restrict__ cnt,
                                                int* __restrict__ row_local,
                                                int* __restrict__ bsum, int n) {
    __shared__ int sd[1024];
    int tid = threadIdx.x;
    int i = blockIdx.x * 1024 + tid;
    int v = (i < n) ? cnt[i] : 0;
    sd[tid] = v;
    __syncthreads();
    for (int off = 1; off < 1024; off <<= 1) {
        int t = (tid >= off) ? sd[tid - off] : 0;
        __syncthreads();
        sd[tid] += t;
        __syncthreads();
    }
    if (i < n) row_local[i] = sd[tid] - v;   // exclusive within block
    if (tid == 1023) bsum[blockIdx.x] = sd[1023];
}

__global__ __launch_bounds__(64) void k_scan2(const int* __restrict__ bsum,
                                              int* __restrict__ boff, int nb,
                                              int* __restrict__ row_start, int n) {
    int lane = threadIdx.x;
    int orig = (lane < nb) ? bsum[lane] : 0;
    int v = orig;
    for (int off = 1; off < 64; off <<= 1) {
        int t = __shfl_up(v, off);
        if (lane >= off) v += t;
    }
    if (lane < nb) boff[lane] = v - orig;
    if (lane == 63) row_start[n] = v;
}

__global__ __launch_bounds__(1024) void k_scan3(const int* __restrict__ row_local,
                                                const int* __restrict__ boff,
                                                const int* __restrict__ cnt,
                                                int* __restrict__ row_start,
                                                float* __restrict__ dinv, int n) {
    int i = blockIdx.x * 1024 + threadIdx.x;
    if (i < n) {
        row_start[i] = row_local[i] + boff[blockIdx.x];
        dinv[i] = rsqrtf((float)(cnt[i] + 1));
    }
}

__global__ void k_scatter(const int* __restrict__ srcv, const int* __restrict__ dstv,
                          const int* __restrict__ row_start, int* __restrict__ cursor,
                          const float* __restrict__ dinv, int* __restrict__ csr_src,
                          float* __restrict__ csr_coef, int e) {
    int i = blockIdx.x * 256 + threadIdx.x;
    if (i < e) {
        int d = dstv[i], s = srcv[i];
        int pos = atomicAdd(&cursor[d], 1);
        int idx = row_start[d] + pos;
        csr_src[idx]  = s;
        csr_coef[idx] = dinv[s] * dinv[d];
    }
}

// ---------------- weight prep: fold GCN W into conv planes ----------------

__global__ __launch_bounds__(256) void k_wprep(const float* __restrict__ gcn_W,
                                               const float* __restrict__ gcn_b,
                                               const float* __restrict__ conv_w,
                                               float* __restrict__ wkp,
                                               float* __restrict__ bkp) {
    int b = blockIdx.x;
    int l = b / 12, k = (b / 4) % 3, cq = b & 3;
    const float* Wg = gcn_W + (size_t)l * 4096;
    const float* cw = conv_w + (size_t)l * 12288;
    int tid = threadIdx.x;
#pragma unroll
    for (int j = 0; j < 4; j++) {
        int idx = j * 256 + tid;            // 0..1023
        int c = cq * 16 + (idx >> 6);
        int o = idx & 63;
        float acc = 0.f;
        for (int d = 0; d < 64; d++)
            acc += Wg[c * 64 + d] * cw[(size_t)(o * 64 + d) * 3 + k];
        wkp[(((size_t)l * 3 + k) * 64 + c) * 64 + o] = acc;
    }
    if (cq == 0 && tid < 64) {
        int o = tid;
        const float* gb = gcn_b + (size_t)l * 64;
        float acc = 0.f;
        for (int d = 0; d < 64; d++)
            acc += gb[d] * cw[(size_t)(o * 64 + d) * 3 + k];
        bkp[((size_t)l * 3 + k) * 64 + o] = acc;
    }
}

// ---------------- embedding (bf16 state out) ----------------

__global__ __launch_bounds__(256) void k_embed(const float* __restrict__ x,
                                               const float* __restrict__ We,
                                               const float* __restrict__ be,
                                               unsigned short* __restrict__ xbf,
                                               int nT) {
    __shared__ float sW[CIN_ * H_];  // [c*64+h]
    __shared__ float sb[H_];
    for (int i = threadIdx.x; i < CIN_ * H_; i += 256) sW[i] = We[i];
    if (threadIdx.x < H_) sb[threadIdx.x] = be[threadIdx.x];
    __syncthreads();
    int h4  = threadIdx.x & 15;
    int ntl = threadIdx.x >> 4;
    int nt  = blockIdx.x * 16 + ntl;
    if (nt >= nT) return;
    const float4* xp = (const float4*)(x + (size_t)nt * CIN_);
    float4 xv4[4];
    xv4[0] = xp[0]; xv4[1] = xp[1]; xv4[2] = xp[2]; xv4[3] = xp[3];
    const float* xs = (const float*)xv4;
    float acc[4];
#pragma unroll
    for (int j = 0; j < 4; j++) acc[j] = sb[h4 * 4 + j];
#pragma unroll
    for (int c = 0; c < CIN_; c++) {
        float4 w = *(const float4*)&sW[c * H_ + h4 * 4];
        float xc = xs[c];
        acc[0] += xc * w.x; acc[1] += xc * w.y; acc[2] += xc * w.z; acc[3] += xc * w.w;
    }
    ushort4 h;
    h.x = f2bf(fmaxf(acc[0], 0.f)); h.y = f2bf(fmaxf(acc[1], 0.f));
    h.z = f2bf(fmaxf(acc[2], 0.f)); h.w = f2bf(fmaxf(acc[3], 0.f));
    *(ushort4*)&xbf[(size_t)nt * H_ + h4 * 4] = h;
}

// ---------------- fused ST layer (bf16 state in/out) ----------------
// 8 nodes / 256 threads (4 waves). LDS = sx fp32 (24576) + edge buf (2560)
// = 27136 B -> 6 blocks/CU = 24 waves (75% occupancy cap).
// Phase A: wave w gathers 2 nodes; edges staged in LDS; x4 unroll of bf16
// neighbor-row loads (8 B/lane chunks).
// Phase C: conv (fp32, from LDS), 2 outputs/thread, folded planes via L1.

#define BFMA(acc, cf, u) { \
    acc.x += cf * bf2f((u).x); \
    acc.y += cf * bf2f((u).y); \
    acc.z += cf * bf2f((u).z); \
    acc.w += cf * bf2f((u).w); }

__global__ __launch_bounds__(256, 6) void k_layer(
        const unsigned short* __restrict__ xin,
        unsigned short* __restrict__ xout,
        const int* __restrict__ row_start, const int* __restrict__ csr_src,
        const float* __restrict__ csr_coef, const float* __restrict__ dinv,
        const float* __restrict__ wkp,    // [3][64][64] folded planes
        const float* __restrict__ bkp,    // [3][64]
        const float* __restrict__ cb,
        const float* __restrict__ bng, const float* __restrict__ bnb,
        const float* __restrict__ bnm, const float* __restrict__ bnv,
        int n) {
    __shared__ float sx[8 * F_];         // 24576 B
    __shared__ int   se[4 * ECAP * 2];   // 2560 B
    int tid = threadIdx.x;
    int n0 = blockIdx.x * 8;
    int wave = tid >> 6, lane = tid & 63;
    int wbase = wave * (ECAP * 2);

    // ---- stage edge lists for this wave's 2 nodes ----
    int begs[2], cnts[2], stgs[2], epos[2];
    {
        int pos = 0;
#pragma unroll
        for (int si = 0; si < 2; si++) {
            int nn = n0 + wave * 2 + si; if (nn >= n) nn = n - 1;
            int beg = row_start[nn], end = row_start[nn + 1];
            int cnt = end - beg;
            int stg = min(cnt, ECAP - pos);
            for (int i = lane; i < stg; i += 64) {
                se[wbase + (pos + i) * 2]     = csr_src[beg + i];
                se[wbase + (pos + i) * 2 + 1] = __float_as_int(csr_coef[beg + i]);
            }
            begs[si] = beg; cnts[si] = cnt; stgs[si] = stg; epos[si] = pos;
            pos += stg;
        }
    }

    // ---- Phase A: gather/aggregate ----
    {
        int c0 = lane, c1 = lane + 64, c2 = lane + 128;   // ushort4 chunks
#pragma unroll
        for (int si = 0; si < 2; si++) {
            int s = wave * 2 + si;
            int nn = n0 + s; if (nn >= n) nn = n - 1;
            float dn = dinv[nn];
            float cs = dn * dn;
            const ushort4* xp = (const ushort4*)(xin + (size_t)nn * F_);
            ushort4 v0 = xp[c0], v1 = xp[c1], v2 = xp[c2];
            float4 a0 = make_float4(0.f, 0.f, 0.f, 0.f);
            float4 a1 = a0, a2 = a0;
            BFMA(a0, cs, v0) BFMA(a1, cs, v1) BFMA(a2, cs, v2)
            int cnt = stgs[si];
            int base = wbase + epos[si] * 2;
            int e = 0;
            for (; e + 3 < cnt; e += 4) {
                int2 p0 = *(const int2*)&se[base + e * 2];
                int2 p1 = *(const int2*)&se[base + e * 2 + 2];
                int2 p2 = *(const int2*)&se[base + e * 2 + 4];
                int2 p3 = *(const int2*)&se[base + e * 2 + 6];
                const ushort4* pA = (const ushort4*)(xin + (size_t)p0.x * F_);
                const ushort4* pB = (const ushort4*)(xin + (size_t)p1.x * F_);
                const ushort4* pC = (const ushort4*)(xin + (size_t)p2.x * F_);
                const ushort4* pD = (const ushort4*)(xin + (size_t)p3.x * F_);
                ushort4 uA0 = pA[c0], uA1 = pA[c1], uA2 = pA[c2];
                ushort4 uB0 = pB[c0], uB1 = pB[c1], uB2 = pB[c2];
                ushort4 uC0 = pC[c0], uC1 = pC[c1], uC2 = pC[c2];
                ushort4 uD0 = pD[c0], uD1 = pD[c1], uD2 = pD[c2];
                float cA = __int_as_float(p0.y), cB = __int_as_float(p1.y);
                float cC = __int_as_float(p2.y), cD = __int_as_float(p3.y);
                BFMA(a0, cA, uA0) BFMA(a1, cA, uA1) BFMA(a2, cA, uA2)
                BFMA(a0, cB, uB0) BFMA(a1, cB, uB1) BFMA(a2, cB, uB2)
                BFMA(a0, cC, uC0) BFMA(a1, cC, uC1) BFMA(a2, cC, uC2)
                BFMA(a0, cD, uD0) BFMA(a1, cD, uD1) BFMA(a2, cD, uD2)
            }
            for (; e < cnt; e++) {
                int2 p0 = *(const int2*)&se[base + e * 2];
                const ushort4* pA = (const ushort4*)(xin + (size_t)p0.x * F_);
                ushort4 uA0 = pA[c0], uA1 = pA[c1], uA2 = pA[c2];
                float cA = __int_as_float(p0.y);
                BFMA(a0, cA, uA0) BFMA(a1, cA, uA1) BFMA(a2, cA, uA2)
            }
            // fallback for edges beyond LDS capacity (essentially never)
            for (int g = begs[si] + stgs[si]; g < begs[si] + cnts[si]; g++) {
                int srcI = csr_src[g];
                float cf = csr_coef[g];
                const ushort4* pA = (const ushort4*)(xin + (size_t)srcI * F_);
                ushort4 uA0 = pA[c0], uA1 = pA[c1], uA2 = pA[c2];
                BFMA(a0, cf, uA0) BFMA(a1, cf, uA1) BFMA(a2, cf, uA2)
            }
            int s3 = s & 3;
            *(float4*)&sx[s * F_ + 4 * (c0 ^ s3)] = a0;
            *(float4*)&sx[s * F_ + 4 * (c1 ^ s3)] = a1;
            *(float4*)&sx[s * F_ + 4 * (c2 ^ s3)] = a2;
        }
    }
    __syncthreads();

    int s  = tid >> 5;         // 0..7
    int o2 = tid & 31;         // outputs o = o2*2, o2*2+1
    int s3 = s & 3;
    const float* xr = &sx[s * F_];
    const float2* w0p = (const float2*)wkp + o2;          // + c*32
    const float2* w1p = (const float2*)(wkp + 4096) + o2; // plane 1
    const float2* w2p = (const float2*)(wkp + 8192) + o2; // plane 2

    // ---- Phase C: conv, all 3 planes per c ----
    float acc2[2][12];
#pragma unroll
    for (int j = 0; j < 2; j++)
#pragma unroll
        for (int t = 0; t < 12; t++) acc2[j][t] = 0.f;
    for (int c = 0; c < 64; c++) {
        float4 q0 = *(const float4*)&xr[4 * ((3 * c + 0) ^ s3)];
        float4 q1 = *(const float4*)&xr[4 * ((3 * c + 1) ^ s3)];
        float4 q2 = *(const float4*)&xr[4 * ((3 * c + 2) ^ s3)];
        float xv[12] = {q0.x, q0.y, q0.z, q0.w, q1.x, q1.y, q1.z, q1.w,
                        q2.x, q2.y, q2.z, q2.w};
        float2 w0 = w0p[c * 32];
        float2 w1 = w1p[c * 32];
        float2 w2 = w2p[c * 32];
#pragma unroll
        for (int t = 1; t < 12; t++) {
            float xc = xv[t - 1];
            acc2[0][t] += w0.x * xc; acc2[1][t] += w0.y * xc;
        }
#pragma unroll
        for (int t = 0; t < 12; t++) {
            float xc = xv[t];
            acc2[0][t] += w1.x * xc; acc2[1][t] += w1.y * xc;
        }
#pragma unroll
        for (int t = 0; t < 11; t++) {
            float xc = xv[t + 1];
            acc2[0][t] += w2.x * xc; acc2[1][t] += w2.y * xc;
        }
    }

    int nn = n0 + s;
    if (nn < n) {
        const unsigned short* rp = xin + (size_t)nn * F_;
        unsigned short* op = xout + (size_t)nn * F_;
#pragma unroll
        for (int j = 0; j < 2; j++) {
            int o = o2 * 2 + j;
            float scale = bng[o] * rsqrtf(bnv[o] + BN_EPS);
            float shift = bnb[o] - bnm[o] * scale;
            float bk0 = bkp[o], bk1 = bkp[64 + o], bk2 = bkp[128 + o];
            float b_all = cb[o] + bk0 + bk1 + bk2;
#pragma unroll
            for (int q = 0; q < 3; q++) {
                ushort4 rv = *(const ushort4*)&rp[o * 12 + q * 4];
                float bias0 = b_all - ((q == 0) ? bk0 : 0.f);
                float bias3 = b_all - ((q == 2) ? bk2 : 0.f);
                float wx = fmaxf((acc2[j][q * 4 + 0] + bias0) * scale + shift + bf2f(rv.x), 0.f);
                float wy = fmaxf((acc2[j][q * 4 + 1] + b_all) * scale + shift + bf2f(rv.y), 0.f);
                float wz = fmaxf((acc2[j][q * 4 + 2] + b_all) * scale + shift + bf2f(rv.z), 0.f);
                float ww = fmaxf((acc2[j][q * 4 + 3] + bias3) * scale + shift + bf2f(rv.w), 0.f);
                ushort4 hb;
                hb.x = f2bf(wx); hb.y = f2bf(wy); hb.z = f2bf(wz); hb.w = f2bf(ww);
                *(ushort4*)&op[o * 12 + q * 4] = hb;
            }
        }
    }
}

// ---------------- dual attention + output MLP (bf16 state in) ----------------

__global__ __launch_bounds__(128) void k_attn(const unsigned short* __restrict__ xst,
        const float* __restrict__ taw1, const float* __restrict__ tab1,
        const float* __restrict__ taw2, const float* __restrict__ tab2,
        const float* __restrict__ faw1, const float* __restrict__ fab1,
        const float* __restrict__ faw2, const float* __restrict__ fab2,
        const float* __restrict__ ow1, const float* __restrict__ ob1,
        const float* __restrict__ ow2, const float* __restrict__ ob2,
        float* __restrict__ out, int n) {
    __shared__ float sT[8 * PAD_ROW];       // [s][h*12+t]
    __shared__ float s_tab1[32], s_taw2[32], s_ob1[32], s_ow2[32];
    __shared__ float s_faw1[72], s_fab1[8], s_faw2[8];
    __shared__ float s_tw[8 * 12];
    __shared__ float s_xf[8 * 65];
    int tid = threadIdx.x;
    int n0 = blockIdx.x * 8;
    if (tid < 32) {
        s_tab1[tid] = tab1[tid]; s_taw2[tid] = taw2[tid];
        s_ob1[tid] = ob1[tid];   s_ow2[tid] = ow2[tid];
    }
    if (tid < 72) s_faw1[tid] = faw1[tid];
    if (tid < 6) { s_fab1[tid] = fab1[tid]; s_faw2[tid] = faw2[tid]; }
    float tb2 = tab2[0], fb2 = fab2[0], o_b2 = ob2[0];
    for (int i = tid; i < 8 * F_; i += 128) {
        int s = i / F_, j = i - s * F_;
        int t = j >> 6, hh = j & 63;
        int nn = n0 + s; if (nn >= n) nn = n - 1;
        sT[s * PAD_ROW + hh * 12 + t] = bf2f(xst[(size_t)nn * F_ + j]);
    }
    __syncthreads();

    int s = tid >> 4, m2 = tid & 15;
    {
        float a0[12], a1[12];
        float b0 = s_tab1[2 * m2], b1 = s_tab1[2 * m2 + 1];
#pragma unroll
        for (int t = 0; t < 12; t++) { a0[t] = b0; a1[t] = b1; }
        const float* xr = &sT[s * PAD_ROW];
        for (int hh = 0; hh < 64; hh++) {
            float4 q0 = *(const float4*)&xr[hh * 12];
            float4 q1 = *(const float4*)&xr[hh * 12 + 4];
            float4 q2 = *(const float4*)&xr[hh * 12 + 8];
            float xv[12] = {q0.x, q0.y, q0.z, q0.w, q1.x, q1.y, q1.z, q1.w, q2.x, q2.y, q2.z, q2.w};
            float2 wv = *(const float2*)&taw1[hh * 32 + 2 * m2];
#pragma unroll
            for (int t = 0; t < 12; t++) { a0[t] += wv.x * xv[t]; a1[t] += wv.y * xv[t]; }
        }
        float w20 = s_taw2[2 * m2], w21 = s_taw2[2 * m2 + 1];
#pragma unroll
        for (int t = 0; t < 12; t++) {
            float p = fmaxf(a0[t], 0.f) * w20 + fmaxf(a1[t], 0.f) * w21;
            p += __shfl_xor(p, 1); p += __shfl_xor(p, 2);
            p += __shfl_xor(p, 4); p += __shfl_xor(p, 8);
            if (m2 == 0) s_tw[s * 12 + t] = p + tb2;
        }
    }
    __syncthreads();

    int wave = tid >> 6, lane = tid & 63;
    for (int q = 0; q < 4; q++) {
        int ss = wave * 4 + q;
        float tw[12];
#pragma unroll
        for (int t = 0; t < 12; t++) tw[t] = s_tw[ss * 12 + t];
        float mx = tw[0];
#pragma unroll
        for (int t = 1; t < 12; t++) mx = fmaxf(mx, tw[t]);
        float sum = 0.f;
#pragma unroll
        for (int t = 0; t < 12; t++) { tw[t] = __expf(tw[t] - mx); sum += tw[t]; }
        float inv = 1.f / sum;
        const float* xr = &sT[ss * PAD_ROW + lane * 12];
        float4 q0 = *(const float4*)(xr);
        float4 q1 = *(const float4*)(xr + 4);
        float4 q2 = *(const float4*)(xr + 8);
        float xv[12] = {q0.x, q0.y, q0.z, q0.w, q1.x, q1.y, q1.z, q1.w, q2.x, q2.y, q2.z, q2.w};
        float xt[12];
#pragma unroll
        for (int t = 0; t < 12; t++) xt[t] = xv[t] * tw[t] * inv;
        float lf = fb2;
#pragma unroll
        for (int mm = 0; mm < 6; mm++) {
            float v = s_fab1[mm];
#pragma unroll
            for (int t = 0; t < 12; t++) v += xt[t] * s_faw1[t * 6 + mm];
            lf += fmaxf(v, 0.f) * s_faw2[mm];
        }
        float m2v = lf;
#pragma unroll
        for (int off = 32; off >= 1; off >>= 1) m2v = fmaxf(m2v, __shfl_xor(m2v, off));
        float e = __expf(lf - m2v);
        float se = e;
#pragma unroll
        for (int off = 32; off >= 1; off >>= 1) se += __shfl_xor(se, off);
        float fwv = e / se;
        float xs = 0.f;
#pragma unroll
        for (int t = 0; t < 12; t++) xs += xt[t];
        s_xf[ss * 65 + lane] = fwv * xs;
    }
    __syncthreads();

    {
        float v0 = s_ob1[2 * m2], v1 = s_ob1[2 * m2 + 1];
        const float* xfp = &s_xf[s * 65];
        for (int hh = 0; hh < 64; hh++) {
            float xv = xfp[hh];
            float2 wv = *(const float2*)&ow1[hh * 32 + 2 * m2];
            v0 += xv * wv.x;
            v1 += xv * wv.y;
        }
        float p = fmaxf(v0, 0.f) * s_ow2[2 * m2] + fmaxf(v1, 0.f) * s_ow2[2 * m2 + 1];
        p += __shfl_xor(p, 1); p += __shfl_xor(p, 2);
        p += __shfl_xor(p, 4); p += __shfl_xor(p, 8);
        if (m2 == 0 && n0 + s < n) out[n0 + s] = p + o_b2;
    }
}

// ---------------- launcher ----------------

extern "C" void kernel_launch(void* const* d_in, const int* in_sizes, int n_in,
                              void* d_out, int out_size, void* d_ws, size_t ws_size,
                              hipStream_t stream) {
    const float* x      = (const float*)d_in[0];
    const int*   ei     = (const int*)d_in[1];
    const float* We     = (const float*)d_in[2];
    const float* be     = (const float*)d_in[3];
    const float* gcn_W  = (const float*)d_in[4];
    const float* gcn_b  = (const float*)d_in[5];
    const float* conv_w = (const float*)d_in[6];
    const float* conv_b = (const float*)d_in[7];
    const float* bn_g   = (const float*)d_in[8];
    const float* bn_b   = (const float*)d_in[9];
    const float* bn_m   = (const float*)d_in[10];
    const float* bn_v   = (const float*)d_in[11];
    const float* ta_w1  = (const float*)d_in[12];
    const float* ta_b1  = (const float*)d_in[13];
    const float* ta_w2  = (const float*)d_in[14];
    const float* ta_b2  = (const float*)d_in[15];
    const float* fa_w1  = (const float*)d_in[16];
    const float* fa_b1  = (const float*)d_in[17];
    const float* fa_w2  = (const float*)d_in[18];
    const float* fa_b2  = (const float*)d_in[19];
    const float* ow1    = (const float*)d_in[20];
    const float* ob1    = (const float*)d_in[21];
    const float* ow2    = (const float*)d_in[22];
    const float* ob2    = (const float*)d_in[23];

    int n = in_sizes[0] / (T_ * CIN_);
    int e = in_sizes[1] / 2;
    const int* srcv = ei;
    const int* dstv = ei + e;

    char* p = (char*)d_ws;
    auto take = [&](size_t bytes) -> void* {
        void* r = (void*)p;
        p += (bytes + 255) & ~(size_t)255;
        return r;
    };
    int*   cnt       = (int*)take((size_t)n * 4);
    int*   cursor    = (int*)take((size_t)n * 4);
    int*   row_start = (int*)take(((size_t)n + 1) * 4);
    int*   row_local = (int*)take((size_t)n * 4);
    int*   bsum      = (int*)take(1024 * 4);
    int*   boff      = (int*)take(1024 * 4);
    float* dinv      = (float*)take((size_t)n * 4);
    int*   csr_src   = (int*)take((size_t)e * 4);
    float* csr_coef  = (float*)take((size_t)e * 4);
    float* wkp       = (float*)take((size_t)3 * 3 * 64 * 64 * 4);
    float* bkp       = (float*)take((size_t)3 * 3 * 64 * 4);
    unsigned short* xabf = (unsigned short*)take((size_t)n * F_ * 2);
    unsigned short* xbbf = (unsigned short*)take((size_t)n * F_ * 2);

    int nb_n = (n + 255) / 256;
    int nb_e = (e + 255) / 256;
    int nb_s = (n + 1023) / 1024;

    k_wprep<<<36, 256, 0, stream>>>(gcn_W, gcn_b, conv_w, wkp, bkp);
    k_init<<<nb_n, 256, 0, stream>>>(cnt, cursor, n);
    k_count<<<nb_e, 256, 0, stream>>>(dstv, cnt, e);
    k_scan1<<<nb_s, 1024, 0, stream>>>(cnt, row_local, bsum, n);
    k_scan2<<<1, 64, 0, stream>>>(bsum, boff, nb_s, row_start, n);
    k_scan3<<<nb_s, 1024, 0, stream>>>(row_local, boff, cnt, row_start, dinv, n);
    k_scatter<<<nb_e, 256, 0, stream>>>(srcv, dstv, row_start, cursor, dinv,
                                        csr_src, csr_coef, e);

    int nT = n * T_;
    k_embed<<<(nT + 15) / 16, 256, 0, stream>>>(x, We, be, xabf, nT);

    int nb8 = (n + 7) / 8;
    const unsigned short* curbf = xabf;
    for (int i = 0; i < 3; i++) {
        unsigned short* nxtbf = (curbf == xabf) ? xbbf : xabf;
        k_layer<<<nb8, 256, 0, stream>>>(curbf, nxtbf,
                                         row_start, csr_src, csr_coef, dinv,
                                         wkp + (size_t)i * 3 * 4096,
                                         bkp + (size_t)i * 3 * 64,
                                         conv_b + (size_t)i * H_,
                                         bn_g + (size_t)i * H_, bn_b + (size_t)i * H_,
                                         bn_m + (size_t)i * H_, bn_v + (size_t)i * H_,
                                         n);
        curbf = nxtbf;
    }

    k_attn<<<nb8, 128, 0, stream>>>(curbf, ta_w1, ta_b1, ta_w2, ta_b2,
                                    fa_w1, fa_b1, fa_w2, fa_b2,
                                    ow1, ob1, ow2, ob2, (float*)d_out, n);
}

// Round 7
// 601.995 us; speedup vs baseline: 2.1187x; 1.1256x over previous
//
#include <hip/hip_runtime.h>
#include <cstddef>
#include <cstdint>

#define T_ 12
#define H_ 64
#define CIN_ 16
#define F_ 768          // H*T
#define PAD_ROW 772
#define BN_EPS 1e-5f
#define ECAP 80         // staged edges per wave (2 nodes, mean deg 16 -> ~32)

typedef float v2f __attribute__((ext_vector_type(2)));

// fp32 -> bf16 round-to-nearest-even
__device__ __forceinline__ unsigned short f2bf(float f) {
    unsigned u = __float_as_uint(f);
    unsigned r = (u + 0x7FFFu + ((u >> 16) & 1u)) >> 16;
    return (unsigned short)r;
}
__device__ __forceinline__ float bf2f(unsigned short h) {
    return __uint_as_float(((unsigned)h) << 16);
}
// unpack 2 bf16 (packed in a uint) -> v2f {elem0, elem1}
__device__ __forceinline__ v2f bf2x2(unsigned u) {
    v2f r;
    r.x = __uint_as_float(u << 16);
    r.y = __uint_as_float(u & 0xFFFF0000u);
    return r;
}
__device__ __forceinline__ v2f pkfma(v2f a, v2f b, v2f c) {
    return __builtin_elementwise_fma(a, b, c);
}

// ---------------- CSR build ----------------

__global__ void k_init(int* __restrict__ cnt, int* __restrict__ cursor, int n) {
    int i = blockIdx.x * 256 + threadIdx.x;
    if (i < n) { cnt[i] = 0; cursor[i] = 0; }
}

__global__ void k_count(const int* __restrict__ dstv, int* __restrict__ cnt, int e) {
    int i = blockIdx.x * 256 + threadIdx.x;
    if (i < e) atomicAdd(&cnt[dstv[i]], 1);
}

__global__ __launch_bounds__(1024) void k_scan1(const int* __restrict__ cnt,
                                                int* __restrict__ row_local,
                                                int* __restrict__ bsum, int n) {
    __shared__ int sd[1024];
    int tid = threadIdx.x;
    int i = blockIdx.x * 1024 + tid;
    int v = (i < n) ? cnt[i] : 0;
    sd[tid] = v;
    __syncthreads();
    for (int off = 1; off < 1024; off <<= 1) {
        int t = (tid >= off) ? sd[tid - off] : 0;
        __syncthreads();
        sd[tid] += t;
        __syncthreads();
    }
    if (i < n) row_local[i] = sd[tid] - v;   // exclusive within block
    if (tid == 1023) bsum[blockIdx.x] = sd[1023];
}

__global__ __launch_bounds__(64) void k_scan2(const int* __restrict__ bsum,
                                              int* __restrict__ boff, int nb,
                                              int* __restrict__ row_start, int n) {
    int lane = threadIdx.x;
    int orig = (lane < nb) ? bsum[lane] : 0;
    int v = orig;
    for (int off = 1; off < 64; off <<= 1) {
        int t = __shfl_up(v, off);
        if (lane >= off) v += t;
    }
    if (lane < nb) boff[lane] = v - orig;
    if (lane == 63) row_start[n] = v;
}

__global__ __launch_bounds__(1024) void k_scan3(const int* __restrict__ row_local,
                                                const int* __restrict__ boff,
                                                const int* __restrict__ cnt,
                                                int* __restrict__ row_start,
                                                float* __restrict__ dinv, int n) {
    int i = blockIdx.x * 1024 + threadIdx.x;
    if (i < n) {
        row_start[i] = row_local[i] + boff[blockIdx.x];
        dinv[i] = rsqrtf((float)(cnt[i] + 1));
    }
}

__global__ void k_scatter(const int* __restrict__ srcv, const int* __restrict__ dstv,
                          const int* __restrict__ row_start, int* __restrict__ cursor,
                          const float* __restrict__ dinv, int* __restrict__ csr_src,
                          float* __restrict__ csr_coef, int e) {
    int i = blockIdx.x * 256 + threadIdx.x;
    if (i < e) {
        int d = dstv[i], s = srcv[i];
        int pos = atomicAdd(&cursor[d], 1);
        int idx = row_start[d] + pos;
        csr_src[idx]  = s;
        csr_coef[idx] = dinv[s] * dinv[d];
    }
}

// ---------------- weight prep: fold GCN W into conv planes ----------------

__global__ __launch_bounds__(256) void k_wprep(const float* __restrict__ gcn_W,
                                               const float* __restrict__ gcn_b,
                                               const float* __restrict__ conv_w,
                                               float* __restrict__ wkp,
                                               float* __restrict__ bkp) {
    int b = blockIdx.x;
    int l = b / 12, k = (b / 4) % 3, cq = b & 3;
    const float* Wg = gcn_W + (size_t)l * 4096;
    const float* cw = conv_w + (size_t)l * 12288;
    int tid = threadIdx.x;
#pragma unroll
    for (int j = 0; j < 4; j++) {
        int idx = j * 256 + tid;            // 0..1023
        int c = cq * 16 + (idx >> 6);
        int o = idx & 63;
        float acc = 0.f;
        for (int d = 0; d < 64; d++)
            acc += Wg[c * 64 + d] * cw[(size_t)(o * 64 + d) * 3 + k];
        wkp[(((size_t)l * 3 + k) * 64 + c) * 64 + o] = acc;
    }
    if (cq == 0 && tid < 64) {
        int o = tid;
        const float* gb = gcn_b + (size_t)l * 64;
        float acc = 0.f;
        for (int d = 0; d < 64; d++)
            acc += gb[d] * cw[(size_t)(o * 64 + d) * 3 + k];
        bkp[((size_t)l * 3 + k) * 64 + o] = acc;
    }
}

// ---------------- embedding (bf16 state out) ----------------

__global__ __launch_bounds__(256) void k_embed(const float* __restrict__ x,
                                               const float* __restrict__ We,
                                               const float* __restrict__ be,
                                               unsigned short* __restrict__ xbf,
                                               int nT) {
    __shared__ float sW[CIN_ * H_];  // [c*64+h]
    __shared__ float sb[H_];
    for (int i = threadIdx.x; i < CIN_ * H_; i += 256) sW[i] = We[i];
    if (threadIdx.x < H_) sb[threadIdx.x] = be[threadIdx.x];
    __syncthreads();
    int h4  = threadIdx.x & 15;
    int ntl = threadIdx.x >> 4;
    int nt  = blockIdx.x * 16 + ntl;
    if (nt >= nT) return;
    const float4* xp = (const float4*)(x + (size_t)nt * CIN_);
    float4 xv4[4];
    xv4[0] = xp[0]; xv4[1] = xp[1]; xv4[2] = xp[2]; xv4[3] = xp[3];
    const float* xs = (const float*)xv4;
    float acc[4];
#pragma unroll
    for (int j = 0; j < 4; j++) acc[j] = sb[h4 * 4 + j];
#pragma unroll
    for (int c = 0; c < CIN_; c++) {
        float4 w = *(const float4*)&sW[c * H_ + h4 * 4];
        float xc = xs[c];
        acc[0] += xc * w.x; acc[1] += xc * w.y; acc[2] += xc * w.z; acc[3] += xc * w.w;
    }
    ushort4 h;
    h.x = f2bf(fmaxf(acc[0], 0.f)); h.y = f2bf(fmaxf(acc[1], 0.f));
    h.z = f2bf(fmaxf(acc[2], 0.f)); h.w = f2bf(fmaxf(acc[3], 0.f));
    *(ushort4*)&xbf[(size_t)nt * H_ + h4 * 4] = h;
}

// ---------------- fused ST layer (bf16 state, packed-fp32 math) ----------------
// 8 nodes / 256 threads (4 waves). LDS = sx fp32 (24576) + edge buf (2560)
// = 27136 B -> 6 blocks/CU = 24 waves.
// Gather: v_pk_fma_f32 on unpacked bf16 pairs (3 VALU / 2 elems).
// Conv: 2 outputs/thread packed in one v2f accumulator -> 34 pk_fma per c.

#define BPK(aL, aH, c2, u) { \
    aL = pkfma(bf2x2((u).x), c2, aL); \
    aH = pkfma(bf2x2((u).y), c2, aH); }

__global__ __launch_bounds__(256, 6) void k_layer(
        const unsigned short* __restrict__ xin,
        unsigned short* __restrict__ xout,
        const int* __restrict__ row_start, const int* __restrict__ csr_src,
        const float* __restrict__ csr_coef, const float* __restrict__ dinv,
        const float* __restrict__ wkp,    // [3][64][64] folded planes
        const float* __restrict__ bkp,    // [3][64]
        const float* __restrict__ cb,
        const float* __restrict__ bng, const float* __restrict__ bnb,
        const float* __restrict__ bnm, const float* __restrict__ bnv,
        int n) {
    __shared__ float sx[8 * F_];         // 24576 B
    __shared__ int   se[4 * ECAP * 2];   // 2560 B
    int tid = threadIdx.x;
    int n0 = blockIdx.x * 8;
    int wave = tid >> 6, lane = tid & 63;
    int wbase = wave * (ECAP * 2);

    // ---- stage edge lists for this wave's 2 nodes ----
    int begs[2], cnts[2], stgs[2], epos[2];
    {
        int pos = 0;
#pragma unroll
        for (int si = 0; si < 2; si++) {
            int nn = n0 + wave * 2 + si; if (nn >= n) nn = n - 1;
            int beg = row_start[nn], end = row_start[nn + 1];
            int cnt = end - beg;
            int stg = min(cnt, ECAP - pos);
            for (int i = lane; i < stg; i += 64) {
                se[wbase + (pos + i) * 2]     = csr_src[beg + i];
                se[wbase + (pos + i) * 2 + 1] = __float_as_int(csr_coef[beg + i]);
            }
            begs[si] = beg; cnts[si] = cnt; stgs[si] = stg; epos[si] = pos;
            pos += stg;
        }
    }

    // ---- Phase A: gather/aggregate ----
    {
        int c0 = lane, c1 = lane + 64, c2i = lane + 128;   // uint2 chunks (8B)
#pragma unroll
        for (int si = 0; si < 2; si++) {
            int s = wave * 2 + si;
            int nn = n0 + s; if (nn >= n) nn = n - 1;
            float dn = dinv[nn];
            float cs = dn * dn;
            v2f cs2 = {cs, cs};
            const uint2* xp = (const uint2*)(xin + (size_t)nn * F_);
            uint2 v0 = xp[c0], v1 = xp[c1], v2 = xp[c2i];
            v2f a0 = bf2x2(v0.x) * cs2, a1 = bf2x2(v0.y) * cs2;
            v2f a2 = bf2x2(v1.x) * cs2, a3 = bf2x2(v1.y) * cs2;
            v2f a4 = bf2x2(v2.x) * cs2, a5 = bf2x2(v2.y) * cs2;
            int cnt = stgs[si];
            int base = wbase + epos[si] * 2;
            int e = 0;
            for (; e + 3 < cnt; e += 4) {
                int2 p0 = *(const int2*)&se[base + e * 2];
                int2 p1 = *(const int2*)&se[base + e * 2 + 2];
                int2 p2 = *(const int2*)&se[base + e * 2 + 4];
                int2 p3 = *(const int2*)&se[base + e * 2 + 6];
                const uint2* pA = (const uint2*)(xin + (size_t)p0.x * F_);
                const uint2* pB = (const uint2*)(xin + (size_t)p1.x * F_);
                const uint2* pC = (const uint2*)(xin + (size_t)p2.x * F_);
                const uint2* pD = (const uint2*)(xin + (size_t)p3.x * F_);
                uint2 uA0 = pA[c0], uA1 = pA[c1], uA2 = pA[c2i];
                uint2 uB0 = pB[c0], uB1 = pB[c1], uB2 = pB[c2i];
                uint2 uC0 = pC[c0], uC1 = pC[c1], uC2 = pC[c2i];
                uint2 uD0 = pD[c0], uD1 = pD[c1], uD2 = pD[c2i];
                float cA = __int_as_float(p0.y), cB = __int_as_float(p1.y);
                float cC = __int_as_float(p2.y), cD = __int_as_float(p3.y);
                v2f cA2 = {cA, cA}, cB2 = {cB, cB}, cC2 = {cC, cC}, cD2 = {cD, cD};
                BPK(a0, a1, cA2, uA0) BPK(a2, a3, cA2, uA1) BPK(a4, a5, cA2, uA2)
                BPK(a0, a1, cB2, uB0) BPK(a2, a3, cB2, uB1) BPK(a4, a5, cB2, uB2)
                BPK(a0, a1, cC2, uC0) BPK(a2, a3, cC2, uC1) BPK(a4, a5, cC2, uC2)
                BPK(a0, a1, cD2, uD0) BPK(a2, a3, cD2, uD1) BPK(a4, a5, cD2, uD2)
            }
            for (; e < cnt; e++) {
                int2 p0 = *(const int2*)&se[base + e * 2];
                const uint2* pA = (const uint2*)(xin + (size_t)p0.x * F_);
                uint2 uA0 = pA[c0], uA1 = pA[c1], uA2 = pA[c2i];
                float cA = __int_as_float(p0.y);
                v2f cA2 = {cA, cA};
                BPK(a0, a1, cA2, uA0) BPK(a2, a3, cA2, uA1) BPK(a4, a5, cA2, uA2)
            }
            // fallback for edges beyond LDS capacity (essentially never)
            for (int g = begs[si] + stgs[si]; g < begs[si] + cnts[si]; g++) {
                int srcI = csr_src[g];
                float cf = csr_coef[g];
                const uint2* pA = (const uint2*)(xin + (size_t)srcI * F_);
                uint2 uA0 = pA[c0], uA1 = pA[c1], uA2 = pA[c2i];
                v2f cf2 = {cf, cf};
                BPK(a0, a1, cf2, uA0) BPK(a2, a3, cf2, uA1) BPK(a4, a5, cf2, uA2)
            }
            int s3 = s & 3;
            float4 f0 = make_float4(a0.x, a0.y, a1.x, a1.y);
            float4 f1 = make_float4(a2.x, a2.y, a3.x, a3.y);
            float4 f2 = make_float4(a4.x, a4.y, a5.x, a5.y);
            *(float4*)&sx[s * F_ + 4 * (c0 ^ s3)] = f0;
            *(float4*)&sx[s * F_ + 4 * (c1 ^ s3)] = f1;
            *(float4*)&sx[s * F_ + 4 * (c2i ^ s3)] = f2;
        }
    }
    __syncthreads();

    int s  = tid >> 5;         // 0..7
    int o2 = tid & 31;         // outputs o = o2*2, o2*2+1
    int s3 = s & 3;
    const float* xr = &sx[s * F_];
    const v2f* w0p = (const v2f*)wkp + o2;          // + c*32
    const v2f* w1p = (const v2f*)(wkp + 4096) + o2; // plane 1
    const v2f* w2p = (const v2f*)(wkp + 8192) + o2; // plane 2

    // ---- Phase C: conv, packed outputs, all 3 planes per c ----
    v2f acc2[12];
#pragma unroll
    for (int t = 0; t < 12; t++) acc2[t] = (v2f){0.f, 0.f};
    for (int c = 0; c < 64; c++) {
        float4 q0 = *(const float4*)&xr[4 * ((3 * c + 0) ^ s3)];
        float4 q1 = *(const float4*)&xr[4 * ((3 * c + 1) ^ s3)];
        float4 q2 = *(const float4*)&xr[4 * ((3 * c + 2) ^ s3)];
        float xv[12] = {q0.x, q0.y, q0.z, q0.w, q1.x, q1.y, q1.z, q1.w,
                        q2.x, q2.y, q2.z, q2.w};
        v2f w0 = w0p[c * 32];
        v2f w1 = w1p[c * 32];
        v2f w2 = w2p[c * 32];
#pragma unroll
        for (int t = 1; t < 12; t++)
            acc2[t] = pkfma(w0, (v2f){xv[t - 1], xv[t - 1]}, acc2[t]);
#pragma unroll
        for (int t = 0; t < 12; t++)
            acc2[t] = pkfma(w1, (v2f){xv[t], xv[t]}, acc2[t]);
#pragma unroll
        for (int t = 0; t < 11; t++)
            acc2[t] = pkfma(w2, (v2f){xv[t + 1], xv[t + 1]}, acc2[t]);
    }

    int nn = n0 + s;
    if (nn < n) {
        const unsigned short* rp = xin + (size_t)nn * F_;
        unsigned short* op = xout + (size_t)nn * F_;
#pragma unroll
        for (int j = 0; j < 2; j++) {
            int o = o2 * 2 + j;
            float scale = bng[o] * rsqrtf(bnv[o] + BN_EPS);
            float shift = bnb[o] - bnm[o] * scale;
            float bk0 = bkp[o], bk1 = bkp[64 + o], bk2 = bkp[128 + o];
            float b_all = cb[o] + bk0 + bk1 + bk2;
#pragma unroll
            for (int q = 0; q < 3; q++) {
                ushort4 rv = *(const ushort4*)&rp[o * 12 + q * 4];
                float bias0 = b_all - ((q == 0) ? bk0 : 0.f);
                float bias3 = b_all - ((q == 2) ? bk2 : 0.f);
                float wx = fmaxf((acc2[q * 4 + 0][j] + bias0) * scale + shift + bf2f(rv.x), 0.f);
                float wy = fmaxf((acc2[q * 4 + 1][j] + b_all) * scale + shift + bf2f(rv.y), 0.f);
                float wz = fmaxf((acc2[q * 4 + 2][j] + b_all) * scale + shift + bf2f(rv.z), 0.f);
                float ww = fmaxf((acc2[q * 4 + 3][j] + bias3) * scale + shift + bf2f(rv.w), 0.f);
                ushort4 hb;
                hb.x = f2bf(wx); hb.y = f2bf(wy); hb.z = f2bf(wz); hb.w = f2bf(ww);
                *(ushort4*)&op[o * 12 + q * 4] = hb;
            }
        }
    }
}

// ---------------- dual attention + output MLP (bf16 state in) ----------------

__global__ __launch_bounds__(128) void k_attn(const unsigned short* __restrict__ xst,
        const float* __restrict__ taw1, const float* __restrict__ tab1,
        const float* __restrict__ taw2, const float* __restrict__ tab2,
        const float* __restrict__ faw1, const float* __restrict__ fab1,
        const float* __restrict__ faw2, const float* __restrict__ fab2,
        const float* __restrict__ ow1, const float* __restrict__ ob1,
        const float* __restrict__ ow2, const float* __restrict__ ob2,
        float* __restrict__ out, int n) {
    __shared__ float sT[8 * PAD_ROW];       // [s][h*12+t]
    __shared__ float s_tab1[32], s_taw2[32], s_ob1[32], s_ow2[32];
    __shared__ float s_faw1[72], s_fab1[8], s_faw2[8];
    __shared__ float s_tw[8 * 12];
    __shared__ float s_xf[8 * 65];
    int tid = threadIdx.x;
    int n0 = blockIdx.x * 8;
    if (tid < 32) {
        s_tab1[tid] = tab1[tid]; s_taw2[tid] = taw2[tid];
        s_ob1[tid] = ob1[tid];   s_ow2[tid] = ow2[tid];
    }
    if (tid < 72) s_faw1[tid] = faw1[tid];
    if (tid < 6) { s_fab1[tid] = fab1[tid]; s_faw2[tid] = faw2[tid]; }
    float tb2 = tab2[0], fb2 = fab2[0], o_b2 = ob2[0];
    for (int i = tid; i < 8 * F_; i += 128) {
        int s = i / F_, j = i - s * F_;
        int t = j >> 6, hh = j & 63;
        int nn = n0 + s; if (nn >= n) nn = n - 1;
        sT[s * PAD_ROW + hh * 12 + t] = bf2f(xst[(size_t)nn * F_ + j]);
    }
    __syncthreads();

    int s = tid >> 4, m2 = tid & 15;
    {
        v2f a[12];
        v2f bb = *((const v2f*)s_tab1 + m2);
#pragma unroll
        for (int t = 0; t < 12; t++) a[t] = bb;
        const float* xr = &sT[s * PAD_ROW];
        const v2f* twp = (const v2f*)taw1 + m2;   // + hh*16
        for (int hh = 0; hh < 64; hh++) {
            float4 q0 = *(const float4*)&xr[hh * 12];
            float4 q1 = *(const float4*)&xr[hh * 12 + 4];
            float4 q2 = *(const float4*)&xr[hh * 12 + 8];
            float xv[12] = {q0.x, q0.y, q0.z, q0.w, q1.x, q1.y, q1.z, q1.w, q2.x, q2.y, q2.z, q2.w};
            v2f wv = twp[hh * 16];
#pragma unroll
            for (int t = 0; t < 12; t++)
                a[t] = pkfma(wv, (v2f){xv[t], xv[t]}, a[t]);
        }
        float w20 = s_taw2[2 * m2], w21 = s_taw2[2 * m2 + 1];
#pragma unroll
        for (int t = 0; t < 12; t++) {
            float p = fmaxf(a[t].x, 0.f) * w20 + fmaxf(a[t].y, 0.f) * w21;
            p += __shfl_xor(p, 1); p += __shfl_xor(p, 2);
            p += __shfl_xor(p, 4); p += __shfl_xor(p, 8);
            if (m2 == 0) s_tw[s * 12 + t] = p + tb2;
        }
    }
    __syncthreads();

    int wave = tid >> 6, lane = tid & 63;
    for (int q = 0; q < 4; q++) {
        int ss = wave * 4 + q;
        float tw[12];
#pragma unroll
        for (int t = 0; t < 12; t++) tw[t] = s_tw[ss * 12 + t];
        float mx = tw[0];
#pragma unroll
        for (int t = 1; t < 12; t++) mx = fmaxf(mx, tw[t]);
        float sum = 0.f;
#pragma unroll
        for (int t = 0; t < 12; t++) { tw[t] = __expf(tw[t] - mx); sum += tw[t]; }
        float inv = 1.f / sum;
        const float* xr = &sT[ss * PAD_ROW + lane * 12];
        float4 q0 = *(const float4*)(xr);
        float4 q1 = *(const float4*)(xr + 4);
        float4 q2 = *(const float4*)(xr + 8);
        float xv[12] = {q0.x, q0.y, q0.z, q0.w, q1.x, q1.y, q1.z, q1.w, q2.x, q2.y, q2.z, q2.w};
        float xt[12];
#pragma unroll
        for (int t = 0; t < 12; t++) xt[t] = xv[t] * tw[t] * inv;
        float lf = fb2;
#pragma unroll
        for (int mm = 0; mm < 6; mm++) {
            float v = s_fab1[mm];
#pragma unroll
            for (int t = 0; t < 12; t++) v += xt[t] * s_faw1[t * 6 + mm];
            lf += fmaxf(v, 0.f) * s_faw2[mm];
        }
        float m2v = lf;
#pragma unroll
        for (int off = 32; off >= 1; off >>= 1) m2v = fmaxf(m2v, __shfl_xor(m2v, off));
        float e = __expf(lf - m2v);
        float se = e;
#pragma unroll
        for (int off = 32; off >= 1; off >>= 1) se += __shfl_xor(se, off);
        float fwv = e / se;
        float xs = 0.f;
#pragma unroll
        for (int t = 0; t < 12; t++) xs += xt[t];
        s_xf[ss * 65 + lane] = fwv * xs;
    }
    __syncthreads();

    {
        float v0 = s_ob1[2 * m2], v1 = s_ob1[2 * m2 + 1];
        const float* xfp = &s_xf[s * 65];
        for (int hh = 0; hh < 64; hh++) {
            float xv = xfp[hh];
            float2 wv = *(const float2*)&ow1[hh * 32 + 2 * m2];
            v0 += xv * wv.x;
            v1 += xv * wv.y;
        }
        float p = fmaxf(v0, 0.f) * s_ow2[2 * m2] + fmaxf(v1, 0.f) * s_ow2[2 * m2 + 1];
        p += __shfl_xor(p, 1); p += __shfl_xor(p, 2);
        p += __shfl_xor(p, 4); p += __shfl_xor(p, 8);
        if (m2 == 0 && n0 + s < n) out[n0 + s] = p + o_b2;
    }
}

// ---------------- launcher ----------------

extern "C" void kernel_launch(void* const* d_in, const int* in_sizes, int n_in,
                              void* d_out, int out_size, void* d_ws, size_t ws_size,
                              hipStream_t stream) {
    const float* x      = (const float*)d_in[0];
    const int*   ei     = (const int*)d_in[1];
    const float* We     = (const float*)d_in[2];
    const float* be     = (const float*)d_in[3];
    const float* gcn_W  = (const float*)d_in[4];
    const float* gcn_b  = (const float*)d_in[5];
    const float* conv_w = (const float*)d_in[6];
    const float* conv_b = (const float*)d_in[7];
    const float* bn_g   = (const float*)d_in[8];
    const float* bn_b   = (const float*)d_in[9];
    const float* bn_m   = (const float*)d_in[10];
    const float* bn_v   = (const float*)d_in[11];
    const float* ta_w1  = (const float*)d_in[12];
    const float* ta_b1  = (const float*)d_in[13];
    const float* ta_w2  = (const float*)d_in[14];
    const float* ta_b2  = (const float*)d_in[15];
    const float* fa_w1  = (const float*)d_in[16];
    const float* fa_b1  = (const float*)d_in[17];
    const float* fa_w2  = (const float*)d_in[18];
    const float* fa_b2  = (const float*)d_in[19];
    const float* ow1    = (const float*)d_in[20];
    const float* ob1    = (const float*)d_in[21];
    const float* ow2    = (const float*)d_in[22];
    const float* ob2    = (const float*)d_in[23];

    int n = in_sizes[0] / (T_ * CIN_);
    int e = in_sizes[1] / 2;
    const int* srcv = ei;
    const int* dstv = ei + e;

    char* p = (char*)d_ws;
    auto take = [&](size_t bytes) -> void* {
        void* r = (void*)p;
        p += (bytes + 255) & ~(size_t)255;
        return r;
    };
    int*   cnt       = (int*)take((size_t)n * 4);
    int*   cursor    = (int*)take((size_t)n * 4);
    int*   row_start = (int*)take(((size_t)n + 1) * 4);
    int*   row_local = (int*)take((size_t)n * 4);
    int*   bsum      = (int*)take(1024 * 4);
    int*   boff      = (int*)take(1024 * 4);
    float* dinv      = (float*)take((size_t)n * 4);
    int*   csr_src   = (int*)take((size_t)e * 4);
    float* csr_coef  = (float*)take((size_t)e * 4);
    float* wkp       = (float*)take((size_t)3 * 3 * 64 * 64 * 4);
    float* bkp       = (float*)take((size_t)3 * 3 * 64 * 4);
    unsigned short* xabf = (unsigned short*)take((size_t)n * F_ * 2);
    unsigned short* xbbf = (unsigned short*)take((size_t)n * F_ * 2);

    int nb_n = (n + 255) / 256;
    int nb_e = (e + 255) / 256;
    int nb_s = (n + 1023) / 1024;

    k_wprep<<<36, 256, 0, stream>>>(gcn_W, gcn_b, conv_w, wkp, bkp);
    k_init<<<nb_n, 256, 0, stream>>>(cnt, cursor, n);
    k_count<<<nb_e, 256, 0, stream>>>(dstv, cnt, e);
    k_scan1<<<nb_s, 1024, 0, stream>>>(cnt, row_local, bsum, n);
    k_scan2<<<1, 64, 0, stream>>>(bsum, boff, nb_s, row_start, n);
    k_scan3<<<nb_s, 1024, 0, stream>>>(row_local, boff, cnt, row_start, dinv, n);
    k_scatter<<<nb_e, 256, 0, stream>>>(srcv, dstv, row_start, cursor, dinv,
                                        csr_src, csr_coef, e);

    int nT = n * T_;
    k_embed<<<(nT + 15) / 16, 256, 0, stream>>>(x, We, be, xabf, nT);

    int nb8 = (n + 7) / 8;
    const unsigned short* curbf = xabf;
    for (int i = 0; i < 3; i++) {
        unsigned short* nxtbf = (curbf == xabf) ? xbbf : xabf;
        k_layer<<<nb8, 256, 0, stream>>>(curbf, nxtbf,
                                         row_start, csr_src, csr_coef, dinv,
                                         wkp + (size_t)i * 3 * 4096,
                                         bkp + (size_t)i * 3 * 64,
                                         conv_b + (size_t)i * H_,
                                         bn_g + (size_t)i * H_, bn_b + (size_t)i * H_,
                                         bn_m + (size_t)i * H_, bn_v + (size_t)i * H_,
                                         n);
        curbf = nxtbf;
    }

    k_attn<<<nb8, 128, 0, stream>>>(curbf, ta_w1, ta_b1, ta_w2, ta_b2,
                                    fa_w1, fa_b1, fa_w2, fa_b2,
                                    ow1, ob1, ow2, ob2, (float*)d_out, n);
}

// Round 8
// 486.956 us; speedup vs baseline: 2.6192x; 1.2362x over previous
//
#include <hip/hip_runtime.h>
#include <cstddef>
#include <cstdint>

#define T_ 12
#define H_ 64
#define CIN_ 16
#define F_ 768          // H*T
#define PAD_ROW 772
#define BN_EPS 1e-5f
#define ECAP 80         // staged edges per wave (2 nodes)
#define RPITCH 88       // sxb row pitch in ushorts (16B-aligned, bank-friendly)

typedef float v2f __attribute__((ext_vector_type(2)));
typedef short s8v __attribute__((ext_vector_type(8)));
typedef float f4v __attribute__((ext_vector_type(4)));

// fp32 -> bf16 round-to-nearest-even
__device__ __forceinline__ unsigned short f2bf(float f) {
    unsigned u = __float_as_uint(f);
    unsigned r = (u + 0x7FFFu + ((u >> 16) & 1u)) >> 16;
    return (unsigned short)r;
}
__device__ __forceinline__ float bf2f(unsigned short h) {
    return __uint_as_float(((unsigned)h) << 16);
}
__device__ __forceinline__ v2f bf2x2(unsigned u) {
    v2f r;
    r.x = __uint_as_float(u << 16);
    r.y = __uint_as_float(u & 0xFFFF0000u);
    return r;
}
__device__ __forceinline__ v2f pkfma(v2f a, v2f b, v2f c) {
    return __builtin_elementwise_fma(a, b, c);
}

// ---------------- CSR build ----------------

__global__ void k_init(int* __restrict__ cnt, int* __restrict__ cursor, int n) {
    int i = blockIdx.x * 256 + threadIdx.x;
    if (i < n) { cnt[i] = 0; cursor[i] = 0; }
}

__global__ void k_count(const int* __restrict__ dstv, int* __restrict__ cnt, int e) {
    int i = blockIdx.x * 256 + threadIdx.x;
    if (i < e) atomicAdd(&cnt[dstv[i]], 1);
}

__global__ __launch_bounds__(1024) void k_scan1(const int* __restrict__ cnt,
                                                int* __restrict__ row_local,
                                                int* __restrict__ bsum, int n) {
    __shared__ int sd[1024];
    int tid = threadIdx.x;
    int i = blockIdx.x * 1024 + tid;
    int v = (i < n) ? cnt[i] : 0;
    sd[tid] = v;
    __syncthreads();
    for (int off = 1; off < 1024; off <<= 1) {
        int t = (tid >= off) ? sd[tid - off] : 0;
        __syncthreads();
        sd[tid] += t;
        __syncthreads();
    }
    if (i < n) row_local[i] = sd[tid] - v;
    if (tid == 1023) bsum[blockIdx.x] = sd[1023];
}

__global__ __launch_bounds__(64) void k_scan2(const int* __restrict__ bsum,
                                              int* __restrict__ boff, int nb,
                                              int* __restrict__ row_start, int n) {
    int lane = threadIdx.x;
    int orig = (lane < nb) ? bsum[lane] : 0;
    int v = orig;
    for (int off = 1; off < 64; off <<= 1) {
        int t = __shfl_up(v, off);
        if (lane >= off) v += t;
    }
    if (lane < nb) boff[lane] = v - orig;
    if (lane == 63) row_start[n] = v;
}

__global__ __launch_bounds__(1024) void k_scan3(const int* __restrict__ row_local,
                                                const int* __restrict__ boff,
                                                const int* __restrict__ cnt,
                                                int* __restrict__ row_start,
                                                float* __restrict__ dinv, int n) {
    int i = blockIdx.x * 1024 + threadIdx.x;
    if (i < n) {
        row_start[i] = row_local[i] + boff[blockIdx.x];
        dinv[i] = rsqrtf((float)(cnt[i] + 1));
    }
}

__global__ void k_scatter(const int* __restrict__ srcv, const int* __restrict__ dstv,
                          const int* __restrict__ row_start, int* __restrict__ cursor,
                          const float* __restrict__ dinv, int* __restrict__ csr_src,
                          float* __restrict__ csr_coef, int e) {
    int i = blockIdx.x * 256 + threadIdx.x;
    if (i < e) {
        int d = dstv[i], s = srcv[i];
        int pos = atomicAdd(&cursor[d], 1);
        int idx = row_start[d] + pos;
        csr_src[idx]  = s;
        csr_coef[idx] = dinv[s] * dinv[d];
    }
}

// ---------------- weight prep: fold GCN W into conv planes ----------------

__global__ __launch_bounds__(256) void k_wprep(const float* __restrict__ gcn_W,
                                               const float* __restrict__ gcn_b,
                                               const float* __restrict__ conv_w,
                                               float* __restrict__ wkp,
                                               float* __restrict__ bkp) {
    int b = blockIdx.x;
    int l = b / 12, k = (b / 4) % 3, cq = b & 3;
    const float* Wg = gcn_W + (size_t)l * 4096;
    const float* cw = conv_w + (size_t)l * 12288;
    int tid = threadIdx.x;
#pragma unroll
    for (int j = 0; j < 4; j++) {
        int idx = j * 256 + tid;
        int c = cq * 16 + (idx >> 6);
        int o = idx & 63;
        float acc = 0.f;
        for (int d = 0; d < 64; d++)
            acc += Wg[c * 64 + d] * cw[(size_t)(o * 64 + d) * 3 + k];
        wkp[(((size_t)l * 3 + k) * 64 + c) * 64 + o] = acc;
    }
    if (cq == 0 && tid < 64) {
        int o = tid;
        const float* gb = gcn_b + (size_t)l * 64;
        float acc = 0.f;
        for (int d = 0; d < 64; d++)
            acc += gb[d] * cw[(size_t)(o * 64 + d) * 3 + k];
        bkp[((size_t)l * 3 + k) * 64 + o] = acc;
    }
}

// pack folded planes into MFMA A-fragment order, bf16:
// wkA[l][mt][ks][lane][j] = bf16( wkp[l][kk][c][o] ),
//   o = mt*16 + (lane&15), k = ks*32 + (lane>>4)*8 + j, kk = k>>6, c = k&63.
__global__ __launch_bounds__(64) void k_wpack(const float* __restrict__ wkp,
                                              unsigned short* __restrict__ wkA) {
    int b = blockIdx.x;              // 0..71
    int l = b / 24, rem = b % 24;
    int mt = rem / 6, ks = rem % 6;
    int lane = threadIdx.x;
    int o = mt * 16 + (lane & 15);
    int kbase = ks * 32 + (lane >> 4) * 8;
#pragma unroll
    for (int j = 0; j < 8; j++) {
        int k = kbase + j;
        int kk = k >> 6, c = k & 63;
        float v = wkp[(((size_t)l * 3 + kk) * 64 + c) * 64 + o];
        wkA[((((size_t)l * 24) + mt * 6 + ks) * 64 + lane) * 8 + j] = f2bf(v);
    }
}

// ---------------- embedding (bf16 state out) ----------------

__global__ __launch_bounds__(256) void k_embed(const float* __restrict__ x,
                                               const float* __restrict__ We,
                                               const float* __restrict__ be,
                                               unsigned short* __restrict__ xbf,
                                               int nT) {
    __shared__ float sW[CIN_ * H_];
    __shared__ float sb[H_];
    for (int i = threadIdx.x; i < CIN_ * H_; i += 256) sW[i] = We[i];
    if (threadIdx.x < H_) sb[threadIdx.x] = be[threadIdx.x];
    __syncthreads();
    int h4  = threadIdx.x & 15;
    int ntl = threadIdx.x >> 4;
    int nt  = blockIdx.x * 16 + ntl;
    if (nt >= nT) return;
    const float4* xp = (const float4*)(x + (size_t)nt * CIN_);
    float4 xv4[4];
    xv4[0] = xp[0]; xv4[1] = xp[1]; xv4[2] = xp[2]; xv4[3] = xp[3];
    const float* xs = (const float*)xv4;
    float acc[4];
#pragma unroll
    for (int j = 0; j < 4; j++) acc[j] = sb[h4 * 4 + j];
#pragma unroll
    for (int c = 0; c < CIN_; c++) {
        float4 w = *(const float4*)&sW[c * H_ + h4 * 4];
        float xc = xs[c];
        acc[0] += xc * w.x; acc[1] += xc * w.y; acc[2] += xc * w.z; acc[3] += xc * w.w;
    }
    ushort4 h;
    h.x = f2bf(fmaxf(acc[0], 0.f)); h.y = f2bf(fmaxf(acc[1], 0.f));
    h.z = f2bf(fmaxf(acc[2], 0.f)); h.w = f2bf(fmaxf(acc[3], 0.f));
    *(ushort4*)&xbf[(size_t)nt * H_ + h4 * 4] = h;
}

// ---------------- fused ST layer: gather (VALU) + conv (MFMA) ----------------
// 8 nodes / 256 threads (4 waves). Gather: wave owns 2 nodes, lane owns c=lane
// (12 contiguous state elems = 3 uint2), accumulates fp32 via v_pk_fma, writes
// bf16 into t-major LDS sxb[s][tt][c] (rows tt=0,13 zeroed = conv padding).
// Conv: GEMM C[o,(s,t)] = sum_k W~[k,o] B[k,(s,t)], K=192, via
// mfma_f32_16x16x32_bf16; wave mt owns o in [16mt,16mt+16); 6 A-frags from
// pre-packed wkA (L1), 36 ds_read_b128 B-frags, 36 MFMA; BN+residual epilogue.

#define BPK(aL, aH, c2, u) { \
    aL = pkfma(bf2x2((u).x), c2, aL); \
    aH = pkfma(bf2x2((u).y), c2, aH); }

__global__ __launch_bounds__(256, 6) void k_layer(
        const unsigned short* __restrict__ xin,
        unsigned short* __restrict__ xout,
        const int* __restrict__ row_start, const int* __restrict__ csr_src,
        const float* __restrict__ csr_coef, const float* __restrict__ dinv,
        const unsigned short* __restrict__ wkA,   // [4][6][64][8] bf16 A-frags
        const float* __restrict__ bkp,            // [3][64]
        const float* __restrict__ cb,
        const float* __restrict__ bng, const float* __restrict__ bnb,
        const float* __restrict__ bnm, const float* __restrict__ bnv,
        int n) {
    __shared__ unsigned short sxb[8 * 14 * RPITCH];   // 19712 B
    __shared__ int se[4 * ECAP * 2];                  // 2560 B
    int tid = threadIdx.x;
    int n0 = blockIdx.x * 8;
    int wave = tid >> 6, lane = tid & 63;
    int wbase = wave * (ECAP * 2);

    // ---- zero the padding rows tt=0 and tt=13 (all 8 nodes) ----
    for (int i = tid; i < 8 * 2 * RPITCH; i += 256) {
        int s = i / (2 * RPITCH);
        int r = i - s * (2 * RPITCH);
        int row = (r < RPITCH) ? 0 : 13;
        int c = (r < RPITCH) ? r : r - RPITCH;
        sxb[s * 14 * RPITCH + row * RPITCH + c] = 0;
    }

    // ---- stage edge lists for this wave's 2 nodes ----
    int begs[2], cnts[2], stgs[2], epos[2];
    {
        int pos = 0;
#pragma unroll
        for (int si = 0; si < 2; si++) {
            int nn = n0 + wave * 2 + si; if (nn >= n) nn = n - 1;
            int beg = row_start[nn], end = row_start[nn + 1];
            int cnt = end - beg;
            int stg = min(cnt, ECAP - pos);
            for (int i = lane; i < stg; i += 64) {
                se[wbase + (pos + i) * 2]     = csr_src[beg + i];
                se[wbase + (pos + i) * 2 + 1] = __float_as_int(csr_coef[beg + i]);
            }
            begs[si] = beg; cnts[si] = cnt; stgs[si] = stg; epos[si] = pos;
            pos += stg;
        }
    }

    // ---- Phase A: gather/aggregate; lane owns c=lane, t=0..11 ----
    {
        int i0 = 3 * lane;   // uint2 index of this lane's 12 elems
#pragma unroll
        for (int si = 0; si < 2; si++) {
            int s = wave * 2 + si;
            int nn = n0 + s; if (nn >= n) nn = n - 1;
            float dn = dinv[nn];
            float cs = dn * dn;
            v2f cs2 = {cs, cs};
            const uint2* xp = (const uint2*)(xin + (size_t)nn * F_);
            uint2 u0 = xp[i0], u1 = xp[i0 + 1], u2 = xp[i0 + 2];
            v2f a0 = bf2x2(u0.x) * cs2, a1 = bf2x2(u0.y) * cs2;
            v2f a2 = bf2x2(u1.x) * cs2, a3 = bf2x2(u1.y) * cs2;
            v2f a4 = bf2x2(u2.x) * cs2, a5 = bf2x2(u2.y) * cs2;
            int cnt = stgs[si];
            int base = wbase + epos[si] * 2;
            int e = 0;
            for (; e + 3 < cnt; e += 4) {
                int2 p0 = *(const int2*)&se[base + e * 2];
                int2 p1 = *(const int2*)&se[base + e * 2 + 2];
                int2 p2 = *(const int2*)&se[base + e * 2 + 4];
                int2 p3 = *(const int2*)&se[base + e * 2 + 6];
                const uint2* pA = (const uint2*)(xin + (size_t)p0.x * F_);
                const uint2* pB = (const uint2*)(xin + (size_t)p1.x * F_);
                const uint2* pC = (const uint2*)(xin + (size_t)p2.x * F_);
                const uint2* pD = (const uint2*)(xin + (size_t)p3.x * F_);
                uint2 uA0 = pA[i0], uA1 = pA[i0 + 1], uA2 = pA[i0 + 2];
                uint2 uB0 = pB[i0], uB1 = pB[i0 + 1], uB2 = pB[i0 + 2];
                uint2 uC0 = pC[i0], uC1 = pC[i0 + 1], uC2 = pC[i0 + 2];
                uint2 uD0 = pD[i0], uD1 = pD[i0 + 1], uD2 = pD[i0 + 2];
                float cA = __int_as_float(p0.y), cB = __int_as_float(p1.y);
                float cC = __int_as_float(p2.y), cD = __int_as_float(p3.y);
                v2f cA2 = {cA, cA}, cB2 = {cB, cB}, cC2 = {cC, cC}, cD2 = {cD, cD};
                BPK(a0, a1, cA2, uA0) BPK(a2, a3, cA2, uA1) BPK(a4, a5, cA2, uA2)
                BPK(a0, a1, cB2, uB0) BPK(a2, a3, cB2, uB1) BPK(a4, a5, cB2, uB2)
                BPK(a0, a1, cC2, uC0) BPK(a2, a3, cC2, uC1) BPK(a4, a5, cC2, uC2)
                BPK(a0, a1, cD2, uD0) BPK(a2, a3, cD2, uD1) BPK(a4, a5, cD2, uD2)
            }
            for (; e < cnt; e++) {
                int2 p0 = *(const int2*)&se[base + e * 2];
                const uint2* pA = (const uint2*)(xin + (size_t)p0.x * F_);
                uint2 uA0 = pA[i0], uA1 = pA[i0 + 1], uA2 = pA[i0 + 2];
                float cA = __int_as_float(p0.y);
                v2f cA2 = {cA, cA};
                BPK(a0, a1, cA2, uA0) BPK(a2, a3, cA2, uA1) BPK(a4, a5, cA2, uA2)
            }
            for (int g = begs[si] + stgs[si]; g < begs[si] + cnts[si]; g++) {
                int srcI = csr_src[g];
                float cf = csr_coef[g];
                const uint2* pA = (const uint2*)(xin + (size_t)srcI * F_);
                uint2 uA0 = pA[i0], uA1 = pA[i0 + 1], uA2 = pA[i0 + 2];
                v2f cf2 = {cf, cf};
                BPK(a0, a1, cf2, uA0) BPK(a2, a3, cf2, uA1) BPK(a4, a5, cf2, uA2)
            }
            // transpose-write bf16: sxb[s][t+1][lane]
            unsigned short* wp = &sxb[s * 14 * RPITCH + RPITCH + lane];
            float vals[12] = {a0.x, a0.y, a1.x, a1.y, a2.x, a2.y,
                              a3.x, a3.y, a4.x, a4.y, a5.x, a5.y};
#pragma unroll
            for (int t = 0; t < 12; t++) wp[t * RPITCH] = f2bf(vals[t]);
        }
    }
    __syncthreads();

    // ---- Phase C: MFMA conv; wave mt owns o in [16*mt, 16*mt+16) ----
    {
        int mt = wave;
        int q = lane >> 4;           // quad
        int l15 = lane & 15;
        // A fragments (bf16, pre-packed): 6 K-steps
        s8v afr[6];
        const s8v* Ap = (const s8v*)wkA;
#pragma unroll
        for (int ks = 0; ks < 6; ks++) afr[ks] = Ap[(mt * 6 + ks) * 64 + lane];
        // BN params for this lane's 4 o's
        int obase = mt * 16 + q * 4;
        float scl[4], shf[4], ball[4], bk0a[4], bk2a[4];
#pragma unroll
        for (int r = 0; r < 4; r++) {
            int o = obase + r;
            float sc = bng[o] * rsqrtf(bnv[o] + BN_EPS);
            scl[r] = sc;
            shf[r] = bnb[o] - bnm[o] * sc;
            float b0 = bkp[o], b1 = bkp[64 + o], b2 = bkp[128 + o];
            ball[r] = cb[o] + b0 + b1 + b2;
            bk0a[r] = b0; bk2a[r] = b2;
        }
#pragma unroll
        for (int nt = 0; nt < 6; nt++) {
            int nidx = nt * 16 + l15;          // 0..95
            int s = nidx / 12, t = nidx - 12 * s;
            const s8v* bp = (const s8v*)&sxb[s * 14 * RPITCH + t * RPITCH + q * 8];
            f4v acc = {0.f, 0.f, 0.f, 0.f};
            // byte offsets 0,64,176,240,352,416 -> s8v idx 0,4,11,15,22,26
            acc = __builtin_amdgcn_mfma_f32_16x16x32_bf16(afr[0], bp[0],  acc, 0, 0, 0);
            acc = __builtin_amdgcn_mfma_f32_16x16x32_bf16(afr[1], bp[4],  acc, 0, 0, 0);
            acc = __builtin_amdgcn_mfma_f32_16x16x32_bf16(afr[2], bp[11], acc, 0, 0, 0);
            acc = __builtin_amdgcn_mfma_f32_16x16x32_bf16(afr[3], bp[15], acc, 0, 0, 0);
            acc = __builtin_amdgcn_mfma_f32_16x16x32_bf16(afr[4], bp[22], acc, 0, 0, 0);
            acc = __builtin_amdgcn_mfma_f32_16x16x32_bf16(afr[5], bp[26], acc, 0, 0, 0);
            // epilogue: BN + bias-edge-correction + residual + ReLU
            int nnode = n0 + s;
            bool valid = (nnode < n);
            int rn = valid ? nnode : (n - 1);
            const unsigned short* rrow = xin + (size_t)rn * F_;
            unsigned short* orow = xout + (size_t)rn * F_;
#pragma unroll
            for (int r = 0; r < 4; r++) {
                int o = obase + r;
                float bias = ball[r];
                if (t == 0)  bias -= bk0a[r];
                if (t == 11) bias -= bk2a[r];
                float v = (acc[r] + bias) * scl[r] + shf[r] + bf2f(rrow[o * 12 + t]);
                v = fmaxf(v, 0.f);
                if (valid) orow[o * 12 + t] = f2bf(v);
            }
        }
    }
}

// ---------------- dual attention + output MLP (bf16 state in) ----------------

__global__ __launch_bounds__(128) void k_attn(const unsigned short* __restrict__ xst,
        const float* __restrict__ taw1, const float* __restrict__ tab1,
        const float* __restrict__ taw2, const float* __restrict__ tab2,
        const float* __restrict__ faw1, const float* __restrict__ fab1,
        const float* __restrict__ faw2, const float* __restrict__ fab2,
        const float* __restrict__ ow1, const float* __restrict__ ob1,
        const float* __restrict__ ow2, const float* __restrict__ ob2,
        float* __restrict__ out, int n) {
    __shared__ float sT[8 * PAD_ROW];       // [s][h*12+t]
    __shared__ float s_tab1[32], s_taw2[32], s_ob1[32], s_ow2[32];
    __shared__ float s_faw1[72], s_fab1[8], s_faw2[8];
    __shared__ float s_tw[8 * 12];
    __shared__ float s_xf[8 * 65];
    int tid = threadIdx.x;
    int n0 = blockIdx.x * 8;
    if (tid < 32) {
        s_tab1[tid] = tab1[tid]; s_taw2[tid] = taw2[tid];
        s_ob1[tid] = ob1[tid];   s_ow2[tid] = ow2[tid];
    }
    if (tid < 72) s_faw1[tid] = faw1[tid];
    if (tid < 6) { s_fab1[tid] = fab1[tid]; s_faw2[tid] = faw2[tid]; }
    float tb2 = tab2[0], fb2 = fab2[0], o_b2 = ob2[0];
    for (int i = tid; i < 8 * F_; i += 128) {
        int s = i / F_, j = i - s * F_;
        int t = j >> 6, hh = j & 63;
        int nn = n0 + s; if (nn >= n) nn = n - 1;
        sT[s * PAD_ROW + hh * 12 + t] = bf2f(xst[(size_t)nn * F_ + j]);
    }
    __syncthreads();

    int s = tid >> 4, m2 = tid & 15;
    {
        v2f a[12];
        v2f bb = *((const v2f*)s_tab1 + m2);
#pragma unroll
        for (int t = 0; t < 12; t++) a[t] = bb;
        const float* xr = &sT[s * PAD_ROW];
        const v2f* twp = (const v2f*)taw1 + m2;
        for (int hh = 0; hh < 64; hh++) {
            float4 q0 = *(const float4*)&xr[hh * 12];
            float4 q1 = *(const float4*)&xr[hh * 12 + 4];
            float4 q2 = *(const float4*)&xr[hh * 12 + 8];
            float xv[12] = {q0.x, q0.y, q0.z, q0.w, q1.x, q1.y, q1.z, q1.w, q2.x, q2.y, q2.z, q2.w};
            v2f wv = twp[hh * 16];
#pragma unroll
            for (int t = 0; t < 12; t++)
                a[t] = pkfma(wv, (v2f){xv[t], xv[t]}, a[t]);
        }
        float w20 = s_taw2[2 * m2], w21 = s_taw2[2 * m2 + 1];
#pragma unroll
        for (int t = 0; t < 12; t++) {
            float p = fmaxf(a[t].x, 0.f) * w20 + fmaxf(a[t].y, 0.f) * w21;
            p += __shfl_xor(p, 1); p += __shfl_xor(p, 2);
            p += __shfl_xor(p, 4); p += __shfl_xor(p, 8);
            if (m2 == 0) s_tw[s * 12 + t] = p + tb2;
        }
    }
    __syncthreads();

    int wave = tid >> 6, lane = tid & 63;
    for (int q = 0; q < 4; q++) {
        int ss = wave * 4 + q;
        float tw[12];
#pragma unroll
        for (int t = 0; t < 12; t++) tw[t] = s_tw[ss * 12 + t];
        float mx = tw[0];
#pragma unroll
        for (int t = 1; t < 12; t++) mx = fmaxf(mx, tw[t]);
        float sum = 0.f;
#pragma unroll
        for (int t = 0; t < 12; t++) { tw[t] = __expf(tw[t] - mx); sum += tw[t]; }
        float inv = 1.f / sum;
        const float* xr = &sT[ss * PAD_ROW + lane * 12];
        float4 q0 = *(const float4*)(xr);
        float4 q1 = *(const float4*)(xr + 4);
        float4 q2 = *(const float4*)(xr + 8);
        float xv[12] = {q0.x, q0.y, q0.z, q0.w, q1.x, q1.y, q1.z, q1.w, q2.x, q2.y, q2.z, q2.w};
        float xt[12];
#pragma unroll
        for (int t = 0; t < 12; t++) xt[t] = xv[t] * tw[t] * inv;
        float lf = fb2;
#pragma unroll
        for (int mm = 0; mm < 6; mm++) {
            float v = s_fab1[mm];
#pragma unroll
            for (int t = 0; t < 12; t++) v += xt[t] * s_faw1[t * 6 + mm];
            lf += fmaxf(v, 0.f) * s_faw2[mm];
        }
        float m2v = lf;
#pragma unroll
        for (int off = 32; off >= 1; off >>= 1) m2v = fmaxf(m2v, __shfl_xor(m2v, off));
        float e = __expf(lf - m2v);
        float se = e;
#pragma unroll
        for (int off = 32; off >= 1; off >>= 1) se += __shfl_xor(se, off);
        float fwv = e / se;
        float xs = 0.f;
#pragma unroll
        for (int t = 0; t < 12; t++) xs += xt[t];
        s_xf[ss * 65 + lane] = fwv * xs;
    }
    __syncthreads();

    {
        float v0 = s_ob1[2 * m2], v1 = s_ob1[2 * m2 + 1];
        const float* xfp = &s_xf[s * 65];
        for (int hh = 0; hh < 64; hh++) {
            float xv = xfp[hh];
            float2 wv = *(const float2*)&ow1[hh * 32 + 2 * m2];
            v0 += xv * wv.x;
            v1 += xv * wv.y;
        }
        float p = fmaxf(v0, 0.f) * s_ow2[2 * m2] + fmaxf(v1, 0.f) * s_ow2[2 * m2 + 1];
        p += __shfl_xor(p, 1); p += __shfl_xor(p, 2);
        p += __shfl_xor(p, 4); p += __shfl_xor(p, 8);
        if (m2 == 0 && n0 + s < n) out[n0 + s] = p + o_b2;
    }
}

// ---------------- launcher ----------------

extern "C" void kernel_launch(void* const* d_in, const int* in_sizes, int n_in,
                              void* d_out, int out_size, void* d_ws, size_t ws_size,
                              hipStream_t stream) {
    const float* x      = (const float*)d_in[0];
    const int*   ei     = (const int*)d_in[1];
    const float* We     = (const float*)d_in[2];
    const float* be     = (const float*)d_in[3];
    const float* gcn_W  = (const float*)d_in[4];
    const float* gcn_b  = (const float*)d_in[5];
    const float* conv_w = (const float*)d_in[6];
    const float* conv_b = (const float*)d_in[7];
    const float* bn_g   = (const float*)d_in[8];
    const float* bn_b   = (const float*)d_in[9];
    const float* bn_m   = (const float*)d_in[10];
    const float* bn_v   = (const float*)d_in[11];
    const float* ta_w1  = (const float*)d_in[12];
    const float* ta_b1  = (const float*)d_in[13];
    const float* ta_w2  = (const float*)d_in[14];
    const float* ta_b2  = (const float*)d_in[15];
    const float* fa_w1  = (const float*)d_in[16];
    const float* fa_b1  = (const float*)d_in[17];
    const float* fa_w2  = (const float*)d_in[18];
    const float* fa_b2  = (const float*)d_in[19];
    const float* ow1    = (const float*)d_in[20];
    const float* ob1    = (const float*)d_in[21];
    const float* ow2    = (const float*)d_in[22];
    const float* ob2    = (const float*)d_in[23];

    int n = in_sizes[0] / (T_ * CIN_);
    int e = in_sizes[1] / 2;
    const int* srcv = ei;
    const int* dstv = ei + e;

    char* p = (char*)d_ws;
    auto take = [&](size_t bytes) -> void* {
        void* r = (void*)p;
        p += (bytes + 255) & ~(size_t)255;
        return r;
    };
    int*   cnt       = (int*)take((size_t)n * 4);
    int*   cursor    = (int*)take((size_t)n * 4);
    int*   row_start = (int*)take(((size_t)n + 1) * 4);
    int*   row_local = (int*)take((size_t)n * 4);
    int*   bsum      = (int*)take(1024 * 4);
    int*   boff      = (int*)take(1024 * 4);
    float* dinv      = (float*)take((size_t)n * 4);
    int*   csr_src   = (int*)take((size_t)e * 4);
    float* csr_coef  = (float*)take((size_t)e * 4);
    float* wkp       = (float*)take((size_t)3 * 3 * 64 * 64 * 4);
    float* bkp       = (float*)take((size_t)3 * 3 * 64 * 4);
    unsigned short* wkA = (unsigned short*)take((size_t)3 * 24 * 64 * 8 * 2);
    unsigned short* xabf = (unsigned short*)take((size_t)n * F_ * 2);
    unsigned short* xbbf = (unsigned short*)take((size_t)n * F_ * 2);

    int nb_n = (n + 255) / 256;
    int nb_e = (e + 255) / 256;
    int nb_s = (n + 1023) / 1024;

    k_wprep<<<36, 256, 0, stream>>>(gcn_W, gcn_b, conv_w, wkp, bkp);
    k_wpack<<<72, 64, 0, stream>>>(wkp, wkA);
    k_init<<<nb_n, 256, 0, stream>>>(cnt, cursor, n);
    k_count<<<nb_e, 256, 0, stream>>>(dstv, cnt, e);
    k_scan1<<<nb_s, 1024, 0, stream>>>(cnt, row_local, bsum, n);
    k_scan2<<<1, 64, 0, stream>>>(bsum, boff, nb_s, row_start, n);
    k_scan3<<<nb_s, 1024, 0, stream>>>(row_local, boff, cnt, row_start, dinv, n);
    k_scatter<<<nb_e, 256, 0, stream>>>(srcv, dstv, row_start, cursor, dinv,
                                        csr_src, csr_coef, e);

    int nT = n * T_;
    k_embed<<<(nT + 15) / 16, 256, 0, stream>>>(x, We, be, xabf, nT);

    int nb8 = (n + 7) / 8;
    const unsigned short* curbf = xabf;
    for (int i = 0; i < 3; i++) {
        unsigned short* nxtbf = (curbf == xabf) ? xbbf : xabf;
        k_layer<<<nb8, 256, 0, stream>>>(curbf, nxtbf,
                                         row_start, csr_src, csr_coef, dinv,
                                         wkA + (size_t)i * 24 * 64 * 8,
                                         bkp + (size_t)i * 3 * 64,
                                         conv_b + (size_t)i * H_,
                                         bn_g + (size_t)i * H_, bn_b + (size_t)i * H_,
                                         bn_m + (size_t)i * H_, bn_v + (size_t)i * H_,
                                         n);
        curbf = nxtbf;
    }

    k_attn<<<nb8, 128, 0, stream>>>(curbf, ta_w1, ta_b1, ta_w2, ta_b2,
                                    fa_w1, fa_b1, fa_w2, fa_b2,
                                    ow1, ob1, ow2, ob2, (float*)d_out, n);
}